// Round 13
// baseline (766.515 us; speedup 1.0000x reference)
//
#include <hip/hip_runtime.h>

#define V_N 50000
#define E_N 800000
#define H_N 128

typedef __bf16 bf16;
typedef bf16 bf16x4 __attribute__((ext_vector_type(4)));
typedef bf16 bf16x8 __attribute__((ext_vector_type(8)));
typedef float f32x4 __attribute__((ext_vector_type(4)));

// PQ all-bf16 row layout: 512 bytes/node = 128 bf16 (P, bias-folded) + 128 bf16 (Q)
#define PQ_STRIDE 512

// Fast silu/sigmoid: v_rcp_f32 instead of the IEEE divide sequence.
__device__ __forceinline__ float silu_f(float x) {
    return x * __builtin_amdgcn_rcpf(1.0f + __expf(-x));
}
__device__ __forceinline__ float sigmoid_f(float x) {
    return __builtin_amdgcn_rcpf(1.0f + __expf(-x));
}

// ---------------------------------------------------------------------------
// Weight prep: transpose all GEMM weights to [N][K] bf16 + build PQ bias
// tables (eb1/cb1 folded into the P half of the projection output).
// ---------------------------------------------------------------------------
__global__ void k_weights(const float* __restrict__ ew1, const float* __restrict__ ew2,
                          const float* __restrict__ nw1, const float* __restrict__ nw2,
                          const float* __restrict__ cw1, const float* __restrict__ cw2,
                          const float* __restrict__ eb1, const float* __restrict__ cb1,
                          bf16* __restrict__ projT, bf16* __restrict__ ew2T,
                          bf16* __restrict__ nw1T, bf16* __restrict__ nw2T,
                          bf16* __restrict__ cprojT, bf16* __restrict__ cw2T,
                          float* __restrict__ biasPQ, float* __restrict__ biasCPQ) {
    int idx = blockIdx.x * 256 + threadIdx.x;
    if (idx < 65536) {                       // projT: 2 layers x [256][128]
        int l = idx >> 15, rem = idx & 32767;
        int n = rem >> 7, k = rem & 127;
        const float* W = ew1 + l * 258 * 128;
        projT[idx] = (bf16)((n < 128) ? W[k * 128 + n] : W[(128 + k) * 128 + (n - 128)]);
    } else if (idx < 98304) {                // ew2T: 2 x [128][128]
        int r = idx - 65536;
        int l = r >> 14, rem = r & 16383;
        int n = rem >> 7, k = rem & 127;
        ew2T[r] = (bf16)(ew2[l * 16384 + k * 128 + n]);
    } else if (idx < 163840) {               // nw1T: 2 x [128][256]
        int r = idx - 98304;
        int l = r >> 15, rem = r & 32767;
        int n = rem >> 8, k = rem & 255;
        nw1T[r] = (bf16)(nw1[l * 32768 + k * 128 + n]);
    } else if (idx < 196608) {               // nw2T: 2 x [128][128]
        int r = idx - 163840;
        int l = r >> 14, rem = r & 16383;
        int n = rem >> 7, k = rem & 127;
        nw2T[r] = (bf16)(nw2[l * 16384 + k * 128 + n]);
    } else if (idx < 229376) {               // cprojT: [256][128]
        int r = idx - 196608;
        int n = r >> 7, k = r & 127;
        cprojT[r] = (bf16)((n < 128) ? cw1[k * 128 + n] : cw1[(128 + k) * 128 + (n - 128)]);
    } else if (idx < 245760) {               // cw2T: [128][128]
        int r = idx - 229376;
        int n = r >> 7, k = r & 127;
        cw2T[r] = (bf16)(cw2[k * 128 + n]);
    } else if (idx < 246272) {               // biasPQ: 2 layers x [256]
        int r = idx - 245760;
        int l = r >> 8, c = r & 255;
        biasPQ[r] = (c < 128) ? eb1[l * 128 + c] : 0.0f;
    } else if (idx < 246528) {               // biasCPQ: [256]
        int c = idx - 246272;
        biasCPQ[c] = (c < 128) ? cb1[c] : 0.0f;
    }
}

// ---------------------------------------------------------------------------
// Counting sort of edges by destination row (ei[0][e]).
// ---------------------------------------------------------------------------
__global__ void k_hist(const int* __restrict__ ei, int* __restrict__ cnt) {
    int e = blockIdx.x * 256 + threadIdx.x;
    if (e < E_N) atomicAdd(&cnt[ei[e]], 1);
}

__global__ __launch_bounds__(1024) void k_scan(const int* __restrict__ cnt,
                                               int* __restrict__ off) {
    __shared__ int wsum[16];
    __shared__ int wscan[16];
    __shared__ int carry_s;
    int tid = threadIdx.x;
    int lane = tid & 63, wid = tid >> 6;
    if (tid == 0) carry_s = 0;
    __syncthreads();
    for (int base = 0; base < V_N; base += 1024) {
        int carry = carry_s;
        int i = base + tid;
        int v = (i < V_N) ? cnt[i] : 0;
        int val = v;
#pragma unroll
        for (int d = 1; d < 64; d <<= 1) {
            int t = __shfl_up(val, d, 64);
            if (lane >= d) val += t;
        }
        if (lane == 63) wsum[wid] = val;
        __syncthreads();
        if (tid == 0) {
            int s = 0;
#pragma unroll
            for (int k = 0; k < 16; k++) { s += wsum[k]; wscan[k] = s; }
        }
        __syncthreads();
        int wbase = wid ? wscan[wid - 1] : 0;
        if (i < V_N) off[i] = carry + wbase + val - v;
        __syncthreads();
        if (tid == 0) carry_s = carry + wscan[15];
        __syncthreads();
    }
}

__global__ void k_scatter(const int* __restrict__ ei, int* __restrict__ off,
                          int* __restrict__ srow, int* __restrict__ scol,
                          int* __restrict__ perm) {
    int e = blockIdx.x * 256 + threadIdx.x;
    if (e >= E_N) return;
    int r = ei[e], c = ei[E_N + e];
    int p = atomicAdd(&off[r], 1);
    srow[p] = r;
    scol[p] = c;
    perm[p] = e;
}

__global__ void k_edgeprep2(const int* __restrict__ perm, const int* __restrict__ srow,
                            const int* __restrict__ scol, const float* __restrict__ x,
                            const float* __restrict__ eattr,
                            float* __restrict__ cd, float* __restrict__ ea2) {
    int p = blockIdx.x * 256 + threadIdx.x;
    if (p >= E_N) return;
    int e = perm[p];
    int r = srow[p], c = scol[p];
    float dx = x[r * 3 + 0] - x[c * 3 + 0];
    float dy = x[r * 3 + 1] - x[c * 3 + 1];
    float dz = x[r * 3 + 2] - x[c * 3 + 2];
    float rad = dx * dx + dy * dy + dz * dz;
    float inv = 1.0f / (sqrtf(rad + 1e-8f) + 1.0f);
    cd[p * 3 + 0] = dx * inv;
    cd[p * 3 + 1] = dy * inv;
    cd[p * 3 + 2] = dz * inv;
    ea2[p * 2 + 0] = rad;
    ea2[p * 2 + 1] = eattr[e];
}

// ---------------------------------------------------------------------------
// Generic node-level GEMM. opq=1 writes the all-bf16 PQ layout (512B rows).
// ---------------------------------------------------------------------------
__global__ __launch_bounds__(256) void k_node_gemm(
    const float* __restrict__ A1, const float* __restrict__ A2,
    const bf16* __restrict__ BT, const float* __restrict__ bias,
    const float* __restrict__ resid, float* __restrict__ C,
    int M, int K, int Ntot, int act, int opq) {
    __shared__ __align__(16) bf16 Asl[64][136];
    __shared__ __align__(16) bf16 Bsl[128][136];
    int tid = threadIdx.x;
    int m0 = blockIdx.x * 64;
    int n0 = blockIdx.y * 128;
    int lane = tid & 63, w = tid >> 6;
    int q = lane >> 4, l15 = lane & 15;

    f32x4 acc[8];
#pragma unroll
    for (int i = 0; i < 8; i++) acc[i] = (f32x4){0.f, 0.f, 0.f, 0.f};

    for (int kc = 0; kc < K; kc += 128) {
        const float* Asrc = (kc == 0) ? A1 : A2;
#pragma unroll
        for (int p = 0; p < 8; p++) {
            int e4 = (p * 256 + tid) * 4;
            int r = e4 >> 7, k = e4 & 127;
            float4 v = {0.f, 0.f, 0.f, 0.f};
            int row = m0 + r;
            if (row < M) v = *(const float4*)&Asrc[(size_t)row * 128 + k];
            bf16x4 b4 = {(bf16)v.x, (bf16)v.y, (bf16)v.z, (bf16)v.w};
            *(bf16x4*)&Asl[r][k] = b4;
        }
#pragma unroll
        for (int p = 0; p < 8; p++) {
            int e8 = (p * 256 + tid) * 8;
            int n = e8 >> 7, k = e8 & 127;
            bf16x8 v = *(const bf16x8*)&BT[(size_t)(n0 + n) * K + kc + k];
            *(bf16x8*)&Bsl[n][k] = v;
        }
        __syncthreads();
        int ar = w * 16 + l15;
#pragma unroll
        for (int kt = 0; kt < 4; kt++) {
            bf16x8 a = *(const bf16x8*)&Asl[ar][kt * 32 + q * 8];
#pragma unroll
            for (int nt = 0; nt < 8; nt++) {
                bf16x8 b = *(const bf16x8*)&Bsl[nt * 16 + l15][kt * 32 + q * 8];
                acc[nt] = __builtin_amdgcn_mfma_f32_16x16x32_bf16(a, b, acc[nt], 0, 0, 0);
            }
        }
        __syncthreads();
    }
#pragma unroll
    for (int nt = 0; nt < 8; nt++) {
        int col = n0 + nt * 16 + l15;
        float bv = bias ? bias[col] : 0.0f;
#pragma unroll
        for (int reg = 0; reg < 4; reg++) {
            int row = m0 + w * 16 + q * 4 + reg;
            if (row < M) {
                float v = acc[nt][reg] + bv;
                if (act) v = silu_f(v);
                if (resid) v += resid[(size_t)row * 128 + (col & 127)];
                if (opq) {
                    *(bf16*)((char*)C + (size_t)row * PQ_STRIDE + col * 2) = (bf16)v;
                } else {
                    C[(size_t)row * Ntot + col] = v;
                }
            }
        }
    }
}

// ---------------------------------------------------------------------------
// Fused node MLP + next projection.
// ---------------------------------------------------------------------------
__global__ __launch_bounds__(256) void k_node_mlp(
    float* __restrict__ A2,             // agg (zeroed in place if zeroA2)
    const bf16* __restrict__ B1T,       // nw1T [128][256]
    const float* __restrict__ b1,
    const bf16* __restrict__ B2T,       // nw2T [128][128]
    const float* __restrict__ b2,
    float* __restrict__ H,              // outh, in/out
    int M, int zeroA2,
    const bf16* __restrict__ PT,        // next proj [256][128]
    const float* __restrict__ pbias,    // 256 (eb1 in P half, 0 in Q half)
    char* __restrict__ PQout) {
    __shared__ __align__(16) bf16 Asl[64][136];
    __shared__ __align__(16) bf16 Bsl[128][136];
    int tid = threadIdx.x;
    int m0 = blockIdx.x * 64;
    int lane = tid & 63, w = tid >> 6;
    int q = lane >> 4, l15 = lane & 15;
    int ar = w * 16 + l15;

    f32x4 acc[8];
#pragma unroll
    for (int i = 0; i < 8; i++) acc[i] = (f32x4){0.f, 0.f, 0.f, 0.f};

    for (int kc = 0; kc < 256; kc += 128) {
        const float* Asrc = (kc == 0) ? H : A2;
#pragma unroll
        for (int p = 0; p < 8; p++) {
            int e4 = (p * 256 + tid) * 4;
            int r = e4 >> 7, k = e4 & 127;
            float4 v = {0.f, 0.f, 0.f, 0.f};
            int row = m0 + r;
            if (row < M) v = *(const float4*)&Asrc[(size_t)row * 128 + k];
            bf16x4 b4 = {(bf16)v.x, (bf16)v.y, (bf16)v.z, (bf16)v.w};
            *(bf16x4*)&Asl[r][k] = b4;
            if (kc == 128 && zeroA2 && row < M) {
                *(float4*)&A2[(size_t)row * 128 + k] = (float4){0.f, 0.f, 0.f, 0.f};
            }
        }
#pragma unroll
        for (int p = 0; p < 8; p++) {
            int e8 = (p * 256 + tid) * 8;
            int n = e8 >> 7, k = e8 & 127;
            bf16x8 v = *(const bf16x8*)&B1T[(size_t)n * 256 + kc + k];
            *(bf16x8*)&Bsl[n][k] = v;
        }
        __syncthreads();
#pragma unroll
        for (int kt = 0; kt < 4; kt++) {
            bf16x8 a = *(const bf16x8*)&Asl[ar][kt * 32 + q * 8];
#pragma unroll
            for (int nt = 0; nt < 8; nt++) {
                bf16x8 b = *(const bf16x8*)&Bsl[nt * 16 + l15][kt * 32 + q * 8];
                acc[nt] = __builtin_amdgcn_mfma_f32_16x16x32_bf16(a, b, acc[nt], 0, 0, 0);
            }
        }
        __syncthreads();
    }
#pragma unroll
    for (int nt = 0; nt < 8; nt++) {
        float bv = b1[nt * 16 + l15];
#pragma unroll
        for (int reg = 0; reg < 4; reg++) {
            int r = w * 16 + q * 4 + reg;
            Asl[r][nt * 16 + l15] = (bf16)silu_f(acc[nt][reg] + bv);
        }
    }
#pragma unroll
    for (int p = 0; p < 8; p++) {
        int e8 = (p * 256 + tid) * 8;
        int n = e8 >> 7, k = e8 & 127;
        *(bf16x8*)&Bsl[n][k] = *(const bf16x8*)&B2T[(size_t)n * 128 + k];
    }
    __syncthreads();
    f32x4 acc2[8];
#pragma unroll
    for (int i = 0; i < 8; i++) acc2[i] = (f32x4){0.f, 0.f, 0.f, 0.f};
#pragma unroll
    for (int kt = 0; kt < 4; kt++) {
        bf16x8 a = *(const bf16x8*)&Asl[ar][kt * 32 + q * 8];
#pragma unroll
        for (int nt = 0; nt < 8; nt++) {
            bf16x8 b = *(const bf16x8*)&Bsl[nt * 16 + l15][kt * 32 + q * 8];
            acc2[nt] = __builtin_amdgcn_mfma_f32_16x16x32_bf16(a, b, acc2[nt], 0, 0, 0);
        }
    }
    // residual add -> Hnew (kept in acc2)
#pragma unroll
    for (int nt = 0; nt < 8; nt++) {
        int col = nt * 16 + l15;
        float bv = b2[col];
#pragma unroll
        for (int reg = 0; reg < 4; reg++) {
            int row = m0 + w * 16 + q * 4 + reg;
            if (row < M) {
                float hv = H[(size_t)row * 128 + col] + acc2[nt][reg] + bv;
                H[(size_t)row * 128 + col] = hv;
                acc2[nt][reg] = hv;
            }
        }
    }
    __syncthreads();   // all GEMM2 LDS reads done
#pragma unroll
    for (int nt = 0; nt < 8; nt++) {
#pragma unroll
        for (int reg = 0; reg < 4; reg++) {
            int r = w * 16 + q * 4 + reg;
            Asl[r][nt * 16 + l15] = (bf16)acc2[nt][reg];
        }
    }
    // fused projection: PQ = Hnew @ PT + pbias, two 128-col halves
    for (int half = 0; half < 2; half++) {
#pragma unroll
        for (int p = 0; p < 8; p++) {
            int e8 = (p * 256 + tid) * 8;
            int n = e8 >> 7, k = e8 & 127;
            *(bf16x8*)&Bsl[n][k] = *(const bf16x8*)&PT[(size_t)(half * 128 + n) * 128 + k];
        }
        __syncthreads();
        f32x4 accp[8];
#pragma unroll
        for (int i = 0; i < 8; i++) accp[i] = (f32x4){0.f, 0.f, 0.f, 0.f};
#pragma unroll
        for (int kt = 0; kt < 4; kt++) {
            bf16x8 a = *(const bf16x8*)&Asl[ar][kt * 32 + q * 8];
#pragma unroll
            for (int nt = 0; nt < 8; nt++) {
                bf16x8 b = *(const bf16x8*)&Bsl[nt * 16 + l15][kt * 32 + q * 8];
                accp[nt] = __builtin_amdgcn_mfma_f32_16x16x32_bf16(a, b, accp[nt], 0, 0, 0);
            }
        }
#pragma unroll
        for (int nt = 0; nt < 8; nt++) {
            int colg = half * 128 + nt * 16 + l15;
            float bv = pbias[colg];
#pragma unroll
            for (int reg = 0; reg < 4; reg++) {
                int row = m0 + w * 16 + q * 4 + reg;
                if (row < M) {
                    *(bf16*)(PQout + (size_t)row * PQ_STRIDE + colg * 2) =
                        (bf16)(accp[nt][reg] + bv);
                }
            }
        }
        __syncthreads();
    }
}

// ---------------------------------------------------------------------------
// Persistent fused GCL edge kernel: 512 threads, 128 sorted edges/tile.
// Transposed FslT reduce scratch with CORRECT 136-element stride (r12's
// [40]-stride cast aliased addresses). Wave-private reduce: each wave reads
// only its own 16-edge range -> no write->read barrier (3 barriers/tile).
// ---------------------------------------------------------------------------
#define NTILES (E_N / 128)

__global__ __launch_bounds__(512, 4) void k_edge_gcl(
    const int* __restrict__ srow, const int* __restrict__ scol,
    const char* __restrict__ PQ,
    const float* __restrict__ ea2, const float* __restrict__ w1c,
    const bf16* __restrict__ ew2T,
    const float* __restrict__ eb2, const float* __restrict__ aw,
    const float* __restrict__ ab, float* __restrict__ agg) {
    __shared__ __align__(16) bf16 Asl[128][136];   // A-tile; overlaid as FslT[col][edge]
    __shared__ __align__(16) bf16 Bsl[128][136];   // persistent weight tile
    __shared__ int rows_s[2][128];
    __shared__ int cols_s[2][128];
    __shared__ float ra_s[2][128], aa_s[2][128];
    int tid = threadIdx.x;
    int lane = tid & 63, w = tid >> 6, q = lane >> 4, l15 = lane & 15;
    int j = (tid & 31) * 4;   // fixed column group per thread
    int eslot = tid >> 5;     // edge sub-slot (0..15)

    // stage B once
#pragma unroll
    for (int p = 0; p < 4; p++) {
        int e8 = (p * 512 + tid) * 8;
        int n = e8 >> 7, k = e8 & 127;
        *(bf16x8*)&Bsl[n][k] = *(const bf16x8*)&ew2T[n * 128 + k];
    }
    float4 w0r = *(const float4*)&w1c[j];
    float4 w1r = *(const float4*)&w1c[128 + j];
    float b2v[8], awv[8];
#pragma unroll
    for (int nt = 0; nt < 8; nt++) {
        b2v[nt] = eb2[nt * 16 + l15];
        awv[nt] = aw[nt * 16 + l15];
    }
    float ab0 = ab[0];

    // prologue: stage meta(t0) into buffer 0
    int t0 = blockIdx.x;
    if (tid < 128) {
        int e = t0 * 128 + tid;
        rows_s[0][tid] = srow[e];
        cols_s[0][tid] = scol[e];
        float2 rr = *(const float2*)&ea2[(size_t)e * 2];
        ra_s[0][tid] = rr.x;
        aa_s[0][tid] = rr.y;
    }

    int b = 0;
    for (int t = t0; t < NTILES; t += gridDim.x, b ^= 1) {
        int tn = t + gridDim.x;
        __syncthreads();   // B1: prev reduce done; meta[b] visible
        if (tn < NTILES && tid < 128) {
            int e = tn * 128 + tid;
            rows_s[b ^ 1][tid] = srow[e];
            cols_s[b ^ 1][tid] = scol[e];
            float2 rr = *(const float2*)&ea2[(size_t)e * 2];
            ra_s[b ^ 1][tid] = rr.x;
            aa_s[b ^ 1][tid] = rr.y;
        }
        // stage A: issue all 16 gathers, then compute
        bf16x4 pb[8];
        bf16x4 qb[8];
#pragma unroll
        for (int p = 0; p < 8; p++) {
            int el = p * 16 + eslot;
            int row = rows_s[b][el], col = cols_s[b][el];
            pb[p] = *(const bf16x4*)(PQ + (size_t)row * PQ_STRIDE + j * 2);
            qb[p] = *(const bf16x4*)(PQ + (size_t)col * PQ_STRIDE + 256 + j * 2);
        }
#pragma unroll
        for (int p = 0; p < 8; p++) {
            int el = p * 16 + eslot;
            float ra = ra_s[b][el], aa = aa_s[b][el];
            float zx = (float)pb[p][0] + (float)qb[p][0];
            float zy = (float)pb[p][1] + (float)qb[p][1];
            float zz = (float)pb[p][2] + (float)qb[p][2];
            float zw = (float)pb[p][3] + (float)qb[p][3];
            zx = fmaf(aa, w1r.x, fmaf(ra, w0r.x, zx));
            zy = fmaf(aa, w1r.y, fmaf(ra, w0r.y, zy));
            zz = fmaf(aa, w1r.z, fmaf(ra, w0r.z, zz));
            zw = fmaf(aa, w1r.w, fmaf(ra, w0r.w, zw));
            bf16x4 b4 = {(bf16)silu_f(zx), (bf16)silu_f(zy),
                         (bf16)silu_f(zz), (bf16)silu_f(zw)};
            *(bf16x4*)&Asl[el][j] = b4;
        }
        __syncthreads();   // B3: Asl ready
        f32x4 acc[8];
#pragma unroll
        for (int i = 0; i < 8; i++) acc[i] = (f32x4){0.f, 0.f, 0.f, 0.f};
        int ar = w * 16 + l15;
#pragma unroll
        for (int kt = 0; kt < 4; kt++) {
            bf16x8 a = *(const bf16x8*)&Asl[ar][kt * 32 + q * 8];
#pragma unroll
            for (int nt = 0; nt < 8; nt++) {
                bf16x8 bb = *(const bf16x8*)&Bsl[nt * 16 + l15][kt * 32 + q * 8];
                acc[nt] = __builtin_amdgcn_mfma_f32_16x16x32_bf16(a, bb, acc[nt], 0, 0, 0);
            }
        }
        // epilogue in regs: silu + attention dot
        float partial[4] = {0.f, 0.f, 0.f, 0.f};
#pragma unroll
        for (int nt = 0; nt < 8; nt++) {
#pragma unroll
            for (int reg = 0; reg < 4; reg++) {
                float mv = silu_f(acc[nt][reg] + b2v[nt]);
                acc[nt][reg] = mv;
                partial[reg] += mv * awv[nt];
            }
        }
        float scale[4];
#pragma unroll
        for (int reg = 0; reg < 4; reg++) {
            float s = partial[reg];
            s += __shfl_xor(s, 1, 16);
            s += __shfl_xor(s, 2, 16);
            s += __shfl_xor(s, 4, 16);
            s += __shfl_xor(s, 8, 16);
            scale[reg] = sigmoid_f(s + ab0) * 0.01f;
        }
        __syncthreads();   // B4: all MFMA reads of Asl done -> overlay FslT
        // FslT[col][edge] with full 136 stride (collision-free).
        // wave w writes ONLY its own edges w*16+q*4+reg for all cols.
#pragma unroll
        for (int reg = 0; reg < 4; reg++) {
            int er = w * 16 + q * 4 + reg;   // this wave's edge
            float sc = scale[reg];
#pragma unroll
            for (int nt = 0; nt < 8; nt++) {
                Asl[nt * 16 + l15][er] = (bf16)(acc[nt][reg] * sc);
            }
        }
        // wave-private reduce: read back ONLY this wave's 16-edge range.
        // Intra-wave LDS ordering -> no barrier.
        int c0 = lane, c1 = lane + 64;
        int eb = w * 16;
        bf16x8 f0a = *(const bf16x8*)&Asl[c0][eb];
        bf16x8 f0b = *(const bf16x8*)&Asl[c0][eb + 8];
        bf16x8 f1a = *(const bf16x8*)&Asl[c1][eb];
        bf16x8 f1b = *(const bf16x8*)&Asl[c1][eb + 8];
        float s0 = 0.f, s1 = 0.f;
#pragma unroll
        for (int el = 0; el < 16; ++el) {
            float v0 = (el < 8) ? (float)f0a[el & 7] : (float)f0b[el & 7];
            float v1 = (el < 8) ? (float)f1a[el & 7] : (float)f1b[el & 7];
            s0 += v0;
            s1 += v1;
            int r = rows_s[b][eb + el];
            int nxt = (el < 15) ? rows_s[b][eb + el + 1] : -1;
            if (r != nxt) {
                atomicAdd(&agg[(size_t)r * 128 + c0], s0);
                atomicAdd(&agg[(size_t)r * 128 + c1], s1);
                s0 = 0.f;
                s1 = 0.f;
            }
        }
    }
}

// ---------------------------------------------------------------------------
// Persistent fused coord-update edge kernel: wave-private Ssl reduce
// (no final barrier; 2 barriers/tile).
// ---------------------------------------------------------------------------
__global__ __launch_bounds__(512, 4) void k_edge_coord(
    const int* __restrict__ srow, const int* __restrict__ scol,
    const char* __restrict__ PQ,
    const float* __restrict__ ea2, const float* __restrict__ c1c,
    const bf16* __restrict__ cw2T,
    const float* __restrict__ cb2, const float* __restrict__ cw3,
    const float* __restrict__ cd, float* __restrict__ xagg) {
    __shared__ __align__(16) bf16 Asl[128][136];
    __shared__ __align__(16) bf16 Bsl[128][136];
    __shared__ int rows_s[2][128];
    __shared__ int cols_s[2][128];
    __shared__ float ra_s[2][128], aa_s[2][128];
    __shared__ float cds[2][384];
    __shared__ float Ssl[128];
    int tid = threadIdx.x;
    int lane = tid & 63, w = tid >> 6, q = lane >> 4, l15 = lane & 15;
    int j = (tid & 31) * 4;
    int eslot = tid >> 5;

#pragma unroll
    for (int p = 0; p < 4; p++) {
        int e8 = (p * 512 + tid) * 8;
        int n = e8 >> 7, k = e8 & 127;
        *(bf16x8*)&Bsl[n][k] = *(const bf16x8*)&cw2T[n * 128 + k];
    }
    float4 w0r = *(const float4*)&c1c[j];
    float4 w1r = *(const float4*)&c1c[128 + j];
    float b2v[8], w3v[8];
#pragma unroll
    for (int nt = 0; nt < 8; nt++) {
        b2v[nt] = cb2[nt * 16 + l15];
        w3v[nt] = cw3[nt * 16 + l15];
    }

    int t0 = blockIdx.x;
    if (tid < 128) {
        int e = t0 * 128 + tid;
        rows_s[0][tid] = srow[e];
        cols_s[0][tid] = scol[e];
        float2 rr = *(const float2*)&ea2[(size_t)e * 2];
        ra_s[0][tid] = rr.x;
        aa_s[0][tid] = rr.y;
    }
    if (tid < 384) cds[0][tid] = cd[(size_t)t0 * 384 + tid];

    int b = 0;
    for (int t = t0; t < NTILES; t += gridDim.x, b ^= 1) {
        int tn = t + gridDim.x;
        __syncthreads();   // B1
        if (tn < NTILES) {
            if (tid < 128) {
                int e = tn * 128 + tid;
                rows_s[b ^ 1][tid] = srow[e];
                cols_s[b ^ 1][tid] = scol[e];
                float2 rr = *(const float2*)&ea2[(size_t)e * 2];
                ra_s[b ^ 1][tid] = rr.x;
                aa_s[b ^ 1][tid] = rr.y;
            }
            if (tid < 384) cds[b ^ 1][tid] = cd[(size_t)tn * 384 + tid];
        }
        bf16x4 pb[8];
        bf16x4 qb[8];
#pragma unroll
        for (int p = 0; p < 8; p++) {
            int el = p * 16 + eslot;
            int row = rows_s[b][el], col = cols_s[b][el];
            pb[p] = *(const bf16x4*)(PQ + (size_t)row * PQ_STRIDE + j * 2);
            qb[p] = *(const bf16x4*)(PQ + (size_t)col * PQ_STRIDE + 256 + j * 2);
        }
#pragma unroll
        for (int p = 0; p < 8; p++) {
            int el = p * 16 + eslot;
            float ra = ra_s[b][el], aa = aa_s[b][el];
            float zx = (float)pb[p][0] + (float)qb[p][0];
            float zy = (float)pb[p][1] + (float)qb[p][1];
            float zz = (float)pb[p][2] + (float)qb[p][2];
            float zw = (float)pb[p][3] + (float)qb[p][3];
            zx = fmaf(aa, w1r.x, fmaf(ra, w0r.x, zx));
            zy = fmaf(aa, w1r.y, fmaf(ra, w0r.y, zy));
            zz = fmaf(aa, w1r.z, fmaf(ra, w0r.z, zz));
            zw = fmaf(aa, w1r.w, fmaf(ra, w0r.w, zw));
            bf16x4 b4 = {(bf16)silu_f(zx), (bf16)silu_f(zy),
                         (bf16)silu_f(zz), (bf16)silu_f(zw)};
            *(bf16x4*)&Asl[el][j] = b4;
        }
        __syncthreads();   // B3
        f32x4 acc[8];
#pragma unroll
        for (int i = 0; i < 8; i++) acc[i] = (f32x4){0.f, 0.f, 0.f, 0.f};
        int ar = w * 16 + l15;
#pragma unroll
        for (int kt = 0; kt < 4; kt++) {
            bf16x8 a = *(const bf16x8*)&Asl[ar][kt * 32 + q * 8];
#pragma unroll
            for (int nt = 0; nt < 8; nt++) {
                bf16x8 bb = *(const bf16x8*)&Bsl[nt * 16 + l15][kt * 32 + q * 8];
                acc[nt] = __builtin_amdgcn_mfma_f32_16x16x32_bf16(a, bb, acc[nt], 0, 0, 0);
            }
        }
        float partial[4] = {0.f, 0.f, 0.f, 0.f};
#pragma unroll
        for (int nt = 0; nt < 8; nt++) {
#pragma unroll
            for (int reg = 0; reg < 4; reg++) {
                float tv = silu_f(acc[nt][reg] + b2v[nt]);
                partial[reg] += tv * w3v[nt];
            }
        }
#pragma unroll
        for (int reg = 0; reg < 4; reg++) {
            float s = partial[reg];
            s += __shfl_xor(s, 1, 16);
            s += __shfl_xor(s, 2, 16);
            s += __shfl_xor(s, 4, 16);
            s += __shfl_xor(s, 8, 16);
            if (l15 == 0) Ssl[w * 16 + q * 4 + reg] = s * 0.01f;
        }
        // wave-private segmented reduce: this wave's 16 edges, lanes 0..2
        // (Ssl writes/reads are intra-wave; no barrier needed)
        if (lane < 3) {
            int d = lane;
            float sum = 0.f;
#pragma unroll
            for (int el = 0; el < 16; ++el) {
                int ge = w * 16 + el;
                sum += cds[b][ge * 3 + d] * Ssl[ge];
                int r = rows_s[b][ge];
                int nxt = (el < 15) ? rows_s[b][ge + 1] : -1;
                if (r != nxt) {
                    atomicAdd(&xagg[(size_t)r * 3 + d], sum);
                    sum = 0.f;
                }
            }
        }
    }
}

__global__ void k_finalx(const float* __restrict__ x, const float* __restrict__ xagg,
                         float* __restrict__ outx) {
    int i = blockIdx.x * 256 + threadIdx.x;
    if (i < V_N * 3) outx[i] = x[i] + xagg[i];
}

// ---------------------------------------------------------------------------
extern "C" void kernel_launch(void* const* d_in, const int* in_sizes, int n_in,
                              void* d_out, int out_size, void* d_ws, size_t ws_size,
                              hipStream_t stream) {
    const float* h = (const float*)d_in[0];
    const float* x = (const float*)d_in[1];
    const int* ei = (const int*)d_in[2];
    const float* eattr = (const float*)d_in[3];
    const float* ew1 = (const float*)d_in[4];
    const float* eb1 = (const float*)d_in[5];
    const float* ew2 = (const float*)d_in[6];
    const float* eb2 = (const float*)d_in[7];
    const float* aw = (const float*)d_in[8];
    const float* ab = (const float*)d_in[9];
    const float* nw1 = (const float*)d_in[10];
    const float* nb1 = (const float*)d_in[11];
    const float* nw2 = (const float*)d_in[12];
    const float* nb2 = (const float*)d_in[13];
    const float* cw1 = (const float*)d_in[14];
    const float* cb1 = (const float*)d_in[15];
    const float* cw2 = (const float*)d_in[16];
    const float* cb2 = (const float*)d_in[17];
    const float* cw3 = (const float*)d_in[18];

    char* ws = (char*)d_ws;
    size_t off_b = 0;
    auto alloc = [&](size_t b) {
        size_t o = off_b;
        off_b += (b + 255) & ~(size_t)255;
        return o;
    };
    float* cd = (float*)(ws + alloc((size_t)E_N * 3 * 4));
    float* ea2 = (float*)(ws + alloc((size_t)E_N * 2 * 4));
    char* PQ = (char*)(ws + alloc((size_t)V_N * PQ_STRIDE));
    float* agg = (float*)(ws + alloc((size_t)V_N * 128 * 4));
    float* xagg = (float*)(ws + alloc((size_t)V_N * 3 * 4));
    bf16* projT = (bf16*)(ws + alloc(2 * 256 * 128 * 2));
    bf16* ew2T = (bf16*)(ws + alloc(2 * 128 * 128 * 2));
    bf16* nw1T = (bf16*)(ws + alloc(2 * 128 * 256 * 2));
    bf16* nw2T = (bf16*)(ws + alloc(2 * 128 * 128 * 2));
    bf16* cprojT = (bf16*)(ws + alloc(256 * 128 * 2));
    bf16* cw2T = (bf16*)(ws + alloc(128 * 128 * 2));
    float* biasPQ = (float*)(ws + alloc(2 * 256 * 4));
    float* biasCPQ = (float*)(ws + alloc(256 * 4));
    int* cnt = (int*)(ws + alloc((size_t)V_N * 4));
    int* offv = (int*)(ws + alloc((size_t)V_N * 4));
    int* srow = (int*)(ws + alloc((size_t)E_N * 4));
    int* scol = (int*)(ws + alloc((size_t)E_N * 4));
    int* perm = (int*)(ws + alloc((size_t)E_N * 4));

    float* outh = (float*)d_out;
    float* outx = outh + (size_t)V_N * 128;

    hipMemcpyAsync(outh, h, (size_t)V_N * 128 * 4, hipMemcpyDeviceToDevice, stream);
    k_weights<<<964, 256, 0, stream>>>(ew1, ew2, nw1, nw2, cw1, cw2, eb1, cb1,
                                       projT, ew2T, nw1T, nw2T, cprojT, cw2T,
                                       biasPQ, biasCPQ);
    // counting sort of edges by row
    hipMemsetAsync(cnt, 0, (size_t)V_N * 4, stream);
    k_hist<<<(E_N + 255) / 256, 256, 0, stream>>>(ei, cnt);
    k_scan<<<1, 1024, 0, stream>>>(cnt, offv);
    k_scatter<<<(E_N + 255) / 256, 256, 0, stream>>>(ei, offv, srow, scol, perm);
    k_edgeprep2<<<(E_N + 255) / 256, 256, 0, stream>>>(perm, srow, scol, x, eattr, cd, ea2);
    hipMemsetAsync(xagg, 0, (size_t)V_N * 3 * 4, stream);
    hipMemsetAsync(agg, 0, (size_t)V_N * 128 * 4, stream);

    int mblocks = (V_N + 63) / 64;
    // layer 0: standalone projection (bias-folded)
    dim3 gproj(mblocks, 2);
    k_node_gemm<<<gproj, 256, 0, stream>>>(outh, nullptr, projT, biasPQ, nullptr,
                                           (float*)PQ, V_N, 128, 256, 0, 1);
    k_edge_gcl<<<512, 512, 0, stream>>>(
        srow, scol, PQ, ea2, ew1 + 256 * 128,
        ew2T, eb2, aw, ab, agg);
    // node MLP 0 (zeroes agg in place) + fused projection for layer 1
    k_node_mlp<<<mblocks, 256, 0, stream>>>(agg, nw1T, nb1, nw2T, nb2, outh, V_N, 1,
                                            projT + 256 * 128, biasPQ + 256, PQ);
    k_edge_gcl<<<512, 512, 0, stream>>>(
        srow, scol, PQ, ea2, ew1 + (size_t)1 * 258 * 128 + 256 * 128,
        ew2T + 128 * 128, eb2 + 128, aw + 128, ab + 1, agg);
    // node MLP 1 + fused coord projection
    k_node_mlp<<<mblocks, 256, 0, stream>>>(agg, nw1T + 128 * 256, nb1 + 128,
                                            nw2T + 128 * 128, nb2 + 128, outh, V_N, 0,
                                            cprojT, biasCPQ, PQ);
    k_edge_coord<<<512, 512, 0, stream>>>(srow, scol, PQ, ea2, cw1 + 256 * 128,
                                          cw2T, cb2, cw3, cd, xagg);
    k_finalx<<<(V_N * 3 + 255) / 256, 256, 0, stream>>>(x, xagg, outx);
}

// Round 14
// 743.080 us; speedup vs baseline: 1.0315x; 1.0315x over previous
//
#include <hip/hip_runtime.h>

#define V_N 50000
#define E_N 800000
#define H_N 128

typedef __bf16 bf16;
typedef bf16 bf16x4 __attribute__((ext_vector_type(4)));
typedef bf16 bf16x8 __attribute__((ext_vector_type(8)));
typedef float f32x4 __attribute__((ext_vector_type(4)));

// PQ all-bf16 row layout: 512 bytes/node = 128 bf16 (P, bias-folded) + 128 bf16 (Q)
#define PQ_STRIDE 512

// Fast silu/sigmoid: v_rcp_f32 instead of the IEEE divide sequence.
__device__ __forceinline__ float silu_f(float x) {
    return x * __builtin_amdgcn_rcpf(1.0f + __expf(-x));
}
__device__ __forceinline__ float sigmoid_f(float x) {
    return __builtin_amdgcn_rcpf(1.0f + __expf(-x));
}

// ---------------------------------------------------------------------------
// Weight prep: transpose all GEMM weights to [N][K] bf16 + build PQ bias
// tables (eb1/cb1 folded into the P half of the projection output).
// ---------------------------------------------------------------------------
__global__ void k_weights(const float* __restrict__ ew1, const float* __restrict__ ew2,
                          const float* __restrict__ nw1, const float* __restrict__ nw2,
                          const float* __restrict__ cw1, const float* __restrict__ cw2,
                          const float* __restrict__ eb1, const float* __restrict__ cb1,
                          bf16* __restrict__ projT, bf16* __restrict__ ew2T,
                          bf16* __restrict__ nw1T, bf16* __restrict__ nw2T,
                          bf16* __restrict__ cprojT, bf16* __restrict__ cw2T,
                          float* __restrict__ biasPQ, float* __restrict__ biasCPQ) {
    int idx = blockIdx.x * 256 + threadIdx.x;
    if (idx < 65536) {                       // projT: 2 layers x [256][128]
        int l = idx >> 15, rem = idx & 32767;
        int n = rem >> 7, k = rem & 127;
        const float* W = ew1 + l * 258 * 128;
        projT[idx] = (bf16)((n < 128) ? W[k * 128 + n] : W[(128 + k) * 128 + (n - 128)]);
    } else if (idx < 98304) {                // ew2T: 2 x [128][128]
        int r = idx - 65536;
        int l = r >> 14, rem = r & 16383;
        int n = rem >> 7, k = rem & 127;
        ew2T[r] = (bf16)(ew2[l * 16384 + k * 128 + n]);
    } else if (idx < 163840) {               // nw1T: 2 x [128][256]
        int r = idx - 98304;
        int l = r >> 15, rem = r & 32767;
        int n = rem >> 8, k = rem & 255;
        nw1T[r] = (bf16)(nw1[l * 32768 + k * 128 + n]);
    } else if (idx < 196608) {               // nw2T: 2 x [128][128]
        int r = idx - 163840;
        int l = r >> 14, rem = r & 16383;
        int n = rem >> 7, k = rem & 127;
        nw2T[r] = (bf16)(nw2[l * 16384 + k * 128 + n]);
    } else if (idx < 229376) {               // cprojT: [256][128]
        int r = idx - 196608;
        int n = r >> 7, k = r & 127;
        cprojT[r] = (bf16)((n < 128) ? cw1[k * 128 + n] : cw1[(128 + k) * 128 + (n - 128)]);
    } else if (idx < 245760) {               // cw2T: [128][128]
        int r = idx - 229376;
        int n = r >> 7, k = r & 127;
        cw2T[r] = (bf16)(cw2[k * 128 + n]);
    } else if (idx < 246272) {               // biasPQ: 2 layers x [256]
        int r = idx - 245760;
        int l = r >> 8, c = r & 255;
        biasPQ[r] = (c < 128) ? eb1[l * 128 + c] : 0.0f;
    } else if (idx < 246528) {               // biasCPQ: [256]
        int c = idx - 246272;
        biasCPQ[c] = (c < 128) ? cb1[c] : 0.0f;
    }
}

// ---------------------------------------------------------------------------
// Counting sort of edges by destination row (ei[0][e]).
// ---------------------------------------------------------------------------
__global__ void k_hist(const int* __restrict__ ei, int* __restrict__ cnt) {
    int e = blockIdx.x * 256 + threadIdx.x;
    if (e < E_N) atomicAdd(&cnt[ei[e]], 1);
}

__global__ __launch_bounds__(1024) void k_scan(const int* __restrict__ cnt,
                                               int* __restrict__ off) {
    __shared__ int wsum[16];
    __shared__ int wscan[16];
    __shared__ int carry_s;
    int tid = threadIdx.x;
    int lane = tid & 63, wid = tid >> 6;
    if (tid == 0) carry_s = 0;
    __syncthreads();
    for (int base = 0; base < V_N; base += 1024) {
        int carry = carry_s;
        int i = base + tid;
        int v = (i < V_N) ? cnt[i] : 0;
        int val = v;
#pragma unroll
        for (int d = 1; d < 64; d <<= 1) {
            int t = __shfl_up(val, d, 64);
            if (lane >= d) val += t;
        }
        if (lane == 63) wsum[wid] = val;
        __syncthreads();
        if (tid == 0) {
            int s = 0;
#pragma unroll
            for (int k = 0; k < 16; k++) { s += wsum[k]; wscan[k] = s; }
        }
        __syncthreads();
        int wbase = wid ? wscan[wid - 1] : 0;
        if (i < V_N) off[i] = carry + wbase + val - v;
        __syncthreads();
        if (tid == 0) carry_s = carry + wscan[15];
        __syncthreads();
    }
}

__global__ void k_scatter(const int* __restrict__ ei, int* __restrict__ off,
                          int* __restrict__ srow, int* __restrict__ scol,
                          int* __restrict__ perm) {
    int e = blockIdx.x * 256 + threadIdx.x;
    if (e >= E_N) return;
    int r = ei[e], c = ei[E_N + e];
    int p = atomicAdd(&off[r], 1);
    srow[p] = r;
    scol[p] = c;
    perm[p] = e;
}

__global__ void k_edgeprep2(const int* __restrict__ perm, const int* __restrict__ srow,
                            const int* __restrict__ scol, const float* __restrict__ x,
                            const float* __restrict__ eattr,
                            float* __restrict__ cd, float* __restrict__ ea2) {
    int p = blockIdx.x * 256 + threadIdx.x;
    if (p >= E_N) return;
    int e = perm[p];
    int r = srow[p], c = scol[p];
    float dx = x[r * 3 + 0] - x[c * 3 + 0];
    float dy = x[r * 3 + 1] - x[c * 3 + 1];
    float dz = x[r * 3 + 2] - x[c * 3 + 2];
    float rad = dx * dx + dy * dy + dz * dz;
    float inv = 1.0f / (sqrtf(rad + 1e-8f) + 1.0f);
    cd[p * 3 + 0] = dx * inv;
    cd[p * 3 + 1] = dy * inv;
    cd[p * 3 + 2] = dz * inv;
    ea2[p * 2 + 0] = rad;
    ea2[p * 2 + 1] = eattr[e];
}

// ---------------------------------------------------------------------------
// Generic node-level GEMM. opq=1 writes the all-bf16 PQ layout (512B rows).
// ---------------------------------------------------------------------------
__global__ __launch_bounds__(256) void k_node_gemm(
    const float* __restrict__ A1, const float* __restrict__ A2,
    const bf16* __restrict__ BT, const float* __restrict__ bias,
    const float* __restrict__ resid, float* __restrict__ C,
    int M, int K, int Ntot, int act, int opq) {
    __shared__ __align__(16) bf16 Asl[64][136];
    __shared__ __align__(16) bf16 Bsl[128][136];
    int tid = threadIdx.x;
    int m0 = blockIdx.x * 64;
    int n0 = blockIdx.y * 128;
    int lane = tid & 63, w = tid >> 6;
    int q = lane >> 4, l15 = lane & 15;

    f32x4 acc[8];
#pragma unroll
    for (int i = 0; i < 8; i++) acc[i] = (f32x4){0.f, 0.f, 0.f, 0.f};

    for (int kc = 0; kc < K; kc += 128) {
        const float* Asrc = (kc == 0) ? A1 : A2;
#pragma unroll
        for (int p = 0; p < 8; p++) {
            int e4 = (p * 256 + tid) * 4;
            int r = e4 >> 7, k = e4 & 127;
            float4 v = {0.f, 0.f, 0.f, 0.f};
            int row = m0 + r;
            if (row < M) v = *(const float4*)&Asrc[(size_t)row * 128 + k];
            bf16x4 b4 = {(bf16)v.x, (bf16)v.y, (bf16)v.z, (bf16)v.w};
            *(bf16x4*)&Asl[r][k] = b4;
        }
#pragma unroll
        for (int p = 0; p < 8; p++) {
            int e8 = (p * 256 + tid) * 8;
            int n = e8 >> 7, k = e8 & 127;
            bf16x8 v = *(const bf16x8*)&BT[(size_t)(n0 + n) * K + kc + k];
            *(bf16x8*)&Bsl[n][k] = v;
        }
        __syncthreads();
        int ar = w * 16 + l15;
#pragma unroll
        for (int kt = 0; kt < 4; kt++) {
            bf16x8 a = *(const bf16x8*)&Asl[ar][kt * 32 + q * 8];
#pragma unroll
            for (int nt = 0; nt < 8; nt++) {
                bf16x8 b = *(const bf16x8*)&Bsl[nt * 16 + l15][kt * 32 + q * 8];
                acc[nt] = __builtin_amdgcn_mfma_f32_16x16x32_bf16(a, b, acc[nt], 0, 0, 0);
            }
        }
        __syncthreads();
    }
#pragma unroll
    for (int nt = 0; nt < 8; nt++) {
        int col = n0 + nt * 16 + l15;
        float bv = bias ? bias[col] : 0.0f;
#pragma unroll
        for (int reg = 0; reg < 4; reg++) {
            int row = m0 + w * 16 + q * 4 + reg;
            if (row < M) {
                float v = acc[nt][reg] + bv;
                if (act) v = silu_f(v);
                if (resid) v += resid[(size_t)row * 128 + (col & 127)];
                if (opq) {
                    *(bf16*)((char*)C + (size_t)row * PQ_STRIDE + col * 2) = (bf16)v;
                } else {
                    C[(size_t)row * Ntot + col] = v;
                }
            }
        }
    }
}

// ---------------------------------------------------------------------------
// Fused node MLP + next projection.
// ---------------------------------------------------------------------------
__global__ __launch_bounds__(256) void k_node_mlp(
    float* __restrict__ A2,             // agg (zeroed in place if zeroA2)
    const bf16* __restrict__ B1T,       // nw1T [128][256]
    const float* __restrict__ b1,
    const bf16* __restrict__ B2T,       // nw2T [128][128]
    const float* __restrict__ b2,
    float* __restrict__ H,              // outh, in/out
    int M, int zeroA2,
    const bf16* __restrict__ PT,        // next proj [256][128]
    const float* __restrict__ pbias,    // 256 (eb1 in P half, 0 in Q half)
    char* __restrict__ PQout) {
    __shared__ __align__(16) bf16 Asl[64][136];
    __shared__ __align__(16) bf16 Bsl[128][136];
    int tid = threadIdx.x;
    int m0 = blockIdx.x * 64;
    int lane = tid & 63, w = tid >> 6;
    int q = lane >> 4, l15 = lane & 15;
    int ar = w * 16 + l15;

    f32x4 acc[8];
#pragma unroll
    for (int i = 0; i < 8; i++) acc[i] = (f32x4){0.f, 0.f, 0.f, 0.f};

    for (int kc = 0; kc < 256; kc += 128) {
        const float* Asrc = (kc == 0) ? H : A2;
#pragma unroll
        for (int p = 0; p < 8; p++) {
            int e4 = (p * 256 + tid) * 4;
            int r = e4 >> 7, k = e4 & 127;
            float4 v = {0.f, 0.f, 0.f, 0.f};
            int row = m0 + r;
            if (row < M) v = *(const float4*)&Asrc[(size_t)row * 128 + k];
            bf16x4 b4 = {(bf16)v.x, (bf16)v.y, (bf16)v.z, (bf16)v.w};
            *(bf16x4*)&Asl[r][k] = b4;
            if (kc == 128 && zeroA2 && row < M) {
                *(float4*)&A2[(size_t)row * 128 + k] = (float4){0.f, 0.f, 0.f, 0.f};
            }
        }
#pragma unroll
        for (int p = 0; p < 8; p++) {
            int e8 = (p * 256 + tid) * 8;
            int n = e8 >> 7, k = e8 & 127;
            bf16x8 v = *(const bf16x8*)&B1T[(size_t)n * 256 + kc + k];
            *(bf16x8*)&Bsl[n][k] = v;
        }
        __syncthreads();
#pragma unroll
        for (int kt = 0; kt < 4; kt++) {
            bf16x8 a = *(const bf16x8*)&Asl[ar][kt * 32 + q * 8];
#pragma unroll
            for (int nt = 0; nt < 8; nt++) {
                bf16x8 b = *(const bf16x8*)&Bsl[nt * 16 + l15][kt * 32 + q * 8];
                acc[nt] = __builtin_amdgcn_mfma_f32_16x16x32_bf16(a, b, acc[nt], 0, 0, 0);
            }
        }
        __syncthreads();
    }
#pragma unroll
    for (int nt = 0; nt < 8; nt++) {
        float bv = b1[nt * 16 + l15];
#pragma unroll
        for (int reg = 0; reg < 4; reg++) {
            int r = w * 16 + q * 4 + reg;
            Asl[r][nt * 16 + l15] = (bf16)silu_f(acc[nt][reg] + bv);
        }
    }
#pragma unroll
    for (int p = 0; p < 8; p++) {
        int e8 = (p * 256 + tid) * 8;
        int n = e8 >> 7, k = e8 & 127;
        *(bf16x8*)&Bsl[n][k] = *(const bf16x8*)&B2T[(size_t)n * 128 + k];
    }
    __syncthreads();
    f32x4 acc2[8];
#pragma unroll
    for (int i = 0; i < 8; i++) acc2[i] = (f32x4){0.f, 0.f, 0.f, 0.f};
#pragma unroll
    for (int kt = 0; kt < 4; kt++) {
        bf16x8 a = *(const bf16x8*)&Asl[ar][kt * 32 + q * 8];
#pragma unroll
        for (int nt = 0; nt < 8; nt++) {
            bf16x8 b = *(const bf16x8*)&Bsl[nt * 16 + l15][kt * 32 + q * 8];
            acc2[nt] = __builtin_amdgcn_mfma_f32_16x16x32_bf16(a, b, acc2[nt], 0, 0, 0);
        }
    }
    // residual add -> Hnew (kept in acc2)
#pragma unroll
    for (int nt = 0; nt < 8; nt++) {
        int col = nt * 16 + l15;
        float bv = b2[col];
#pragma unroll
        for (int reg = 0; reg < 4; reg++) {
            int row = m0 + w * 16 + q * 4 + reg;
            if (row < M) {
                float hv = H[(size_t)row * 128 + col] + acc2[nt][reg] + bv;
                H[(size_t)row * 128 + col] = hv;
                acc2[nt][reg] = hv;
            }
        }
    }
    __syncthreads();   // all GEMM2 LDS reads done
#pragma unroll
    for (int nt = 0; nt < 8; nt++) {
#pragma unroll
        for (int reg = 0; reg < 4; reg++) {
            int r = w * 16 + q * 4 + reg;
            Asl[r][nt * 16 + l15] = (bf16)acc2[nt][reg];
        }
    }
    // fused projection: PQ = Hnew @ PT + pbias, two 128-col halves
    for (int half = 0; half < 2; half++) {
#pragma unroll
        for (int p = 0; p < 8; p++) {
            int e8 = (p * 256 + tid) * 8;
            int n = e8 >> 7, k = e8 & 127;
            *(bf16x8*)&Bsl[n][k] = *(const bf16x8*)&PT[(size_t)(half * 128 + n) * 128 + k];
        }
        __syncthreads();
        f32x4 accp[8];
#pragma unroll
        for (int i = 0; i < 8; i++) accp[i] = (f32x4){0.f, 0.f, 0.f, 0.f};
#pragma unroll
        for (int kt = 0; kt < 4; kt++) {
            bf16x8 a = *(const bf16x8*)&Asl[ar][kt * 32 + q * 8];
#pragma unroll
            for (int nt = 0; nt < 8; nt++) {
                bf16x8 b = *(const bf16x8*)&Bsl[nt * 16 + l15][kt * 32 + q * 8];
                accp[nt] = __builtin_amdgcn_mfma_f32_16x16x32_bf16(a, b, accp[nt], 0, 0, 0);
            }
        }
#pragma unroll
        for (int nt = 0; nt < 8; nt++) {
            int colg = half * 128 + nt * 16 + l15;
            float bv = pbias[colg];
#pragma unroll
            for (int reg = 0; reg < 4; reg++) {
                int row = m0 + w * 16 + q * 4 + reg;
                if (row < M) {
                    *(bf16*)(PQout + (size_t)row * PQ_STRIDE + colg * 2) =
                        (bf16)(accp[nt][reg] + bv);
                }
            }
        }
        __syncthreads();
    }
}

// ---------------------------------------------------------------------------
// Persistent fused GCL edge kernel: 512 threads, 128 sorted edges/tile.
// Stage-A mapping: 16 lanes/edge x 8 cols/lane -> half the VMEM/LDS
// instructions (8x16B loads, 4x b128 writes per thread). Wave-private
// transposed reduce (r13, collision-free 136 stride), 3 barriers/tile.
// ---------------------------------------------------------------------------
#define NTILES (E_N / 128)

__global__ __launch_bounds__(512, 4) void k_edge_gcl(
    const int* __restrict__ srow, const int* __restrict__ scol,
    const char* __restrict__ PQ,
    const float* __restrict__ ea2, const float* __restrict__ w1c,
    const bf16* __restrict__ ew2T,
    const float* __restrict__ eb2, const float* __restrict__ aw,
    const float* __restrict__ ab, float* __restrict__ agg) {
    __shared__ __align__(16) bf16 Asl[128][136];   // A-tile; overlaid as FslT[col][edge]
    __shared__ __align__(16) bf16 Bsl[128][136];   // persistent weight tile
    __shared__ int rows_s[2][128];
    __shared__ int cols_s[2][128];
    __shared__ float ra_s[2][128], aa_s[2][128];
    int tid = threadIdx.x;
    int lane = tid & 63, w = tid >> 6, q = lane >> 4, l15 = lane & 15;
    int j8 = (tid & 15) * 8;   // fixed 8-column group per thread
    int es16 = tid >> 4;       // edge sub-slot (0..31)

    // stage B once
#pragma unroll
    for (int p = 0; p < 4; p++) {
        int e8 = (p * 512 + tid) * 8;
        int n = e8 >> 7, k = e8 & 127;
        *(bf16x8*)&Bsl[n][k] = *(const bf16x8*)&ew2T[n * 128 + k];
    }
    float4 w0a = *(const float4*)&w1c[j8];
    float4 w0b = *(const float4*)&w1c[j8 + 4];
    float4 w1a = *(const float4*)&w1c[128 + j8];
    float4 w1b = *(const float4*)&w1c[128 + j8 + 4];
    float b2v[8], awv[8];
#pragma unroll
    for (int nt = 0; nt < 8; nt++) {
        b2v[nt] = eb2[nt * 16 + l15];
        awv[nt] = aw[nt * 16 + l15];
    }
    float ab0 = ab[0];

    // prologue: stage meta(t0) into buffer 0
    int t0 = blockIdx.x;
    if (tid < 128) {
        int e = t0 * 128 + tid;
        rows_s[0][tid] = srow[e];
        cols_s[0][tid] = scol[e];
        float2 rr = *(const float2*)&ea2[(size_t)e * 2];
        ra_s[0][tid] = rr.x;
        aa_s[0][tid] = rr.y;
    }

    int b = 0;
    for (int t = t0; t < NTILES; t += gridDim.x, b ^= 1) {
        int tn = t + gridDim.x;
        __syncthreads();   // B1: prev reduce done; meta[b] visible
        if (tn < NTILES && tid < 128) {
            int e = tn * 128 + tid;
            rows_s[b ^ 1][tid] = srow[e];
            cols_s[b ^ 1][tid] = scol[e];
            float2 rr = *(const float2*)&ea2[(size_t)e * 2];
            ra_s[b ^ 1][tid] = rr.x;
            aa_s[b ^ 1][tid] = rr.y;
        }
        // stage A: 4 passes x 32 edges, 8 cols/thread; issue all loads first
        bf16x8 pb[4];
        bf16x8 qb[4];
#pragma unroll
        for (int p = 0; p < 4; p++) {
            int el = p * 32 + es16;
            int row = rows_s[b][el], col = cols_s[b][el];
            pb[p] = *(const bf16x8*)(PQ + (size_t)row * PQ_STRIDE + j8 * 2);
            qb[p] = *(const bf16x8*)(PQ + (size_t)col * PQ_STRIDE + 256 + j8 * 2);
        }
#pragma unroll
        for (int p = 0; p < 4; p++) {
            int el = p * 32 + es16;
            float ra = ra_s[b][el], aa = aa_s[b][el];
            bf16x8 m8;
            float z;
            z = (float)pb[p][0] + (float)qb[p][0]; z = fmaf(aa, w1a.x, fmaf(ra, w0a.x, z)); m8[0] = (bf16)silu_f(z);
            z = (float)pb[p][1] + (float)qb[p][1]; z = fmaf(aa, w1a.y, fmaf(ra, w0a.y, z)); m8[1] = (bf16)silu_f(z);
            z = (float)pb[p][2] + (float)qb[p][2]; z = fmaf(aa, w1a.z, fmaf(ra, w0a.z, z)); m8[2] = (bf16)silu_f(z);
            z = (float)pb[p][3] + (float)qb[p][3]; z = fmaf(aa, w1a.w, fmaf(ra, w0a.w, z)); m8[3] = (bf16)silu_f(z);
            z = (float)pb[p][4] + (float)qb[p][4]; z = fmaf(aa, w1b.x, fmaf(ra, w0b.x, z)); m8[4] = (bf16)silu_f(z);
            z = (float)pb[p][5] + (float)qb[p][5]; z = fmaf(aa, w1b.y, fmaf(ra, w0b.y, z)); m8[5] = (bf16)silu_f(z);
            z = (float)pb[p][6] + (float)qb[p][6]; z = fmaf(aa, w1b.z, fmaf(ra, w0b.z, z)); m8[6] = (bf16)silu_f(z);
            z = (float)pb[p][7] + (float)qb[p][7]; z = fmaf(aa, w1b.w, fmaf(ra, w0b.w, z)); m8[7] = (bf16)silu_f(z);
            *(bf16x8*)&Asl[el][j8] = m8;
        }
        __syncthreads();   // B3: Asl ready
        f32x4 acc[8];
#pragma unroll
        for (int i = 0; i < 8; i++) acc[i] = (f32x4){0.f, 0.f, 0.f, 0.f};
        int ar = w * 16 + l15;
#pragma unroll
        for (int kt = 0; kt < 4; kt++) {
            bf16x8 a = *(const bf16x8*)&Asl[ar][kt * 32 + q * 8];
#pragma unroll
            for (int nt = 0; nt < 8; nt++) {
                bf16x8 bb = *(const bf16x8*)&Bsl[nt * 16 + l15][kt * 32 + q * 8];
                acc[nt] = __builtin_amdgcn_mfma_f32_16x16x32_bf16(a, bb, acc[nt], 0, 0, 0);
            }
        }
        // epilogue in regs: silu + attention dot
        float partial[4] = {0.f, 0.f, 0.f, 0.f};
#pragma unroll
        for (int nt = 0; nt < 8; nt++) {
#pragma unroll
            for (int reg = 0; reg < 4; reg++) {
                float mv = silu_f(acc[nt][reg] + b2v[nt]);
                acc[nt][reg] = mv;
                partial[reg] += mv * awv[nt];
            }
        }
        float scale[4];
#pragma unroll
        for (int reg = 0; reg < 4; reg++) {
            float s = partial[reg];
            s += __shfl_xor(s, 1, 16);
            s += __shfl_xor(s, 2, 16);
            s += __shfl_xor(s, 4, 16);
            s += __shfl_xor(s, 8, 16);
            scale[reg] = sigmoid_f(s + ab0) * 0.01f;
        }
        __syncthreads();   // B4: all MFMA reads of Asl done -> overlay FslT
        // FslT[col][edge] with full 136 stride (collision-free).
#pragma unroll
        for (int reg = 0; reg < 4; reg++) {
            int er = w * 16 + q * 4 + reg;   // this wave's edge
            float sc = scale[reg];
#pragma unroll
            for (int nt = 0; nt < 8; nt++) {
                Asl[nt * 16 + l15][er] = (bf16)(acc[nt][reg] * sc);
            }
        }
        // wave-private reduce: read back ONLY this wave's 16-edge range.
        int c0 = lane, c1 = lane + 64;
        int eb = w * 16;
        bf16x8 f0a = *(const bf16x8*)&Asl[c0][eb];
        bf16x8 f0b = *(const bf16x8*)&Asl[c0][eb + 8];
        bf16x8 f1a = *(const bf16x8*)&Asl[c1][eb];
        bf16x8 f1b = *(const bf16x8*)&Asl[c1][eb + 8];
        float s0 = 0.f, s1 = 0.f;
#pragma unroll
        for (int el = 0; el < 16; ++el) {
            float v0 = (el < 8) ? (float)f0a[el & 7] : (float)f0b[el & 7];
            float v1 = (el < 8) ? (float)f1a[el & 7] : (float)f1b[el & 7];
            s0 += v0;
            s1 += v1;
            int r = rows_s[b][eb + el];
            int nxt = (el < 15) ? rows_s[b][eb + el + 1] : -1;
            if (r != nxt) {
                atomicAdd(&agg[(size_t)r * 128 + c0], s0);
                atomicAdd(&agg[(size_t)r * 128 + c1], s1);
                s0 = 0.f;
                s1 = 0.f;
            }
        }
    }
}

// ---------------------------------------------------------------------------
// Persistent fused coord-update edge kernel: same 8-col stage-A mapping,
// wave-private Ssl reduce (2 barriers/tile).
// ---------------------------------------------------------------------------
__global__ __launch_bounds__(512, 4) void k_edge_coord(
    const int* __restrict__ srow, const int* __restrict__ scol,
    const char* __restrict__ PQ,
    const float* __restrict__ ea2, const float* __restrict__ c1c,
    const bf16* __restrict__ cw2T,
    const float* __restrict__ cb2, const float* __restrict__ cw3,
    const float* __restrict__ cd, float* __restrict__ xagg) {
    __shared__ __align__(16) bf16 Asl[128][136];
    __shared__ __align__(16) bf16 Bsl[128][136];
    __shared__ int rows_s[2][128];
    __shared__ int cols_s[2][128];
    __shared__ float ra_s[2][128], aa_s[2][128];
    __shared__ float cds[2][384];
    __shared__ float Ssl[128];
    int tid = threadIdx.x;
    int lane = tid & 63, w = tid >> 6, q = lane >> 4, l15 = lane & 15;
    int j8 = (tid & 15) * 8;
    int es16 = tid >> 4;

#pragma unroll
    for (int p = 0; p < 4; p++) {
        int e8 = (p * 512 + tid) * 8;
        int n = e8 >> 7, k = e8 & 127;
        *(bf16x8*)&Bsl[n][k] = *(const bf16x8*)&cw2T[n * 128 + k];
    }
    float4 w0a = *(const float4*)&c1c[j8];
    float4 w0b = *(const float4*)&c1c[j8 + 4];
    float4 w1a = *(const float4*)&c1c[128 + j8];
    float4 w1b = *(const float4*)&c1c[128 + j8 + 4];
    float b2v[8], w3v[8];
#pragma unroll
    for (int nt = 0; nt < 8; nt++) {
        b2v[nt] = cb2[nt * 16 + l15];
        w3v[nt] = cw3[nt * 16 + l15];
    }

    int t0 = blockIdx.x;
    if (tid < 128) {
        int e = t0 * 128 + tid;
        rows_s[0][tid] = srow[e];
        cols_s[0][tid] = scol[e];
        float2 rr = *(const float2*)&ea2[(size_t)e * 2];
        ra_s[0][tid] = rr.x;
        aa_s[0][tid] = rr.y;
    }
    if (tid < 384) cds[0][tid] = cd[(size_t)t0 * 384 + tid];

    int b = 0;
    for (int t = t0; t < NTILES; t += gridDim.x, b ^= 1) {
        int tn = t + gridDim.x;
        __syncthreads();   // B1
        if (tn < NTILES) {
            if (tid < 128) {
                int e = tn * 128 + tid;
                rows_s[b ^ 1][tid] = srow[e];
                cols_s[b ^ 1][tid] = scol[e];
                float2 rr = *(const float2*)&ea2[(size_t)e * 2];
                ra_s[b ^ 1][tid] = rr.x;
                aa_s[b ^ 1][tid] = rr.y;
            }
            if (tid < 384) cds[b ^ 1][tid] = cd[(size_t)tn * 384 + tid];
        }
        bf16x8 pb[4];
        bf16x8 qb[4];
#pragma unroll
        for (int p = 0; p < 4; p++) {
            int el = p * 32 + es16;
            int row = rows_s[b][el], col = cols_s[b][el];
            pb[p] = *(const bf16x8*)(PQ + (size_t)row * PQ_STRIDE + j8 * 2);
            qb[p] = *(const bf16x8*)(PQ + (size_t)col * PQ_STRIDE + 256 + j8 * 2);
        }
#pragma unroll
        for (int p = 0; p < 4; p++) {
            int el = p * 32 + es16;
            float ra = ra_s[b][el], aa = aa_s[b][el];
            bf16x8 m8;
            float z;
            z = (float)pb[p][0] + (float)qb[p][0]; z = fmaf(aa, w1a.x, fmaf(ra, w0a.x, z)); m8[0] = (bf16)silu_f(z);
            z = (float)pb[p][1] + (float)qb[p][1]; z = fmaf(aa, w1a.y, fmaf(ra, w0a.y, z)); m8[1] = (bf16)silu_f(z);
            z = (float)pb[p][2] + (float)qb[p][2]; z = fmaf(aa, w1a.z, fmaf(ra, w0a.z, z)); m8[2] = (bf16)silu_f(z);
            z = (float)pb[p][3] + (float)qb[p][3]; z = fmaf(aa, w1a.w, fmaf(ra, w0a.w, z)); m8[3] = (bf16)silu_f(z);
            z = (float)pb[p][4] + (float)qb[p][4]; z = fmaf(aa, w1b.x, fmaf(ra, w0b.x, z)); m8[4] = (bf16)silu_f(z);
            z = (float)pb[p][5] + (float)qb[p][5]; z = fmaf(aa, w1b.y, fmaf(ra, w0b.y, z)); m8[5] = (bf16)silu_f(z);
            z = (float)pb[p][6] + (float)qb[p][6]; z = fmaf(aa, w1b.z, fmaf(ra, w0b.z, z)); m8[6] = (bf16)silu_f(z);
            z = (float)pb[p][7] + (float)qb[p][7]; z = fmaf(aa, w1b.w, fmaf(ra, w0b.w, z)); m8[7] = (bf16)silu_f(z);
            *(bf16x8*)&Asl[el][j8] = m8;
        }
        __syncthreads();   // B3
        f32x4 acc[8];
#pragma unroll
        for (int i = 0; i < 8; i++) acc[i] = (f32x4){0.f, 0.f, 0.f, 0.f};
        int ar = w * 16 + l15;
#pragma unroll
        for (int kt = 0; kt < 4; kt++) {
            bf16x8 a = *(const bf16x8*)&Asl[ar][kt * 32 + q * 8];
#pragma unroll
            for (int nt = 0; nt < 8; nt++) {
                bf16x8 bb = *(const bf16x8*)&Bsl[nt * 16 + l15][kt * 32 + q * 8];
                acc[nt] = __builtin_amdgcn_mfma_f32_16x16x32_bf16(a, bb, acc[nt], 0, 0, 0);
            }
        }
        float partial[4] = {0.f, 0.f, 0.f, 0.f};
#pragma unroll
        for (int nt = 0; nt < 8; nt++) {
#pragma unroll
            for (int reg = 0; reg < 4; reg++) {
                float tv = silu_f(acc[nt][reg] + b2v[nt]);
                partial[reg] += tv * w3v[nt];
            }
        }
#pragma unroll
        for (int reg = 0; reg < 4; reg++) {
            float s = partial[reg];
            s += __shfl_xor(s, 1, 16);
            s += __shfl_xor(s, 2, 16);
            s += __shfl_xor(s, 4, 16);
            s += __shfl_xor(s, 8, 16);
            if (l15 == 0) Ssl[w * 16 + q * 4 + reg] = s * 0.01f;
        }
        // wave-private segmented reduce (intra-wave Ssl, no barrier)
        if (lane < 3) {
            int d = lane;
            float sum = 0.f;
#pragma unroll
            for (int el = 0; el < 16; ++el) {
                int ge = w * 16 + el;
                sum += cds[b][ge * 3 + d] * Ssl[ge];
                int r = rows_s[b][ge];
                int nxt = (el < 15) ? rows_s[b][ge + 1] : -1;
                if (r != nxt) {
                    atomicAdd(&xagg[(size_t)r * 3 + d], sum);
                    sum = 0.f;
                }
            }
        }
    }
}

__global__ void k_finalx(const float* __restrict__ x, const float* __restrict__ xagg,
                         float* __restrict__ outx) {
    int i = blockIdx.x * 256 + threadIdx.x;
    if (i < V_N * 3) outx[i] = x[i] + xagg[i];
}

// ---------------------------------------------------------------------------
extern "C" void kernel_launch(void* const* d_in, const int* in_sizes, int n_in,
                              void* d_out, int out_size, void* d_ws, size_t ws_size,
                              hipStream_t stream) {
    const float* h = (const float*)d_in[0];
    const float* x = (const float*)d_in[1];
    const int* ei = (const int*)d_in[2];
    const float* eattr = (const float*)d_in[3];
    const float* ew1 = (const float*)d_in[4];
    const float* eb1 = (const float*)d_in[5];
    const float* ew2 = (const float*)d_in[6];
    const float* eb2 = (const float*)d_in[7];
    const float* aw = (const float*)d_in[8];
    const float* ab = (const float*)d_in[9];
    const float* nw1 = (const float*)d_in[10];
    const float* nb1 = (const float*)d_in[11];
    const float* nw2 = (const float*)d_in[12];
    const float* nb2 = (const float*)d_in[13];
    const float* cw1 = (const float*)d_in[14];
    const float* cb1 = (const float*)d_in[15];
    const float* cw2 = (const float*)d_in[16];
    const float* cb2 = (const float*)d_in[17];
    const float* cw3 = (const float*)d_in[18];

    char* ws = (char*)d_ws;
    size_t off_b = 0;
    auto alloc = [&](size_t b) {
        size_t o = off_b;
        off_b += (b + 255) & ~(size_t)255;
        return o;
    };
    float* cd = (float*)(ws + alloc((size_t)E_N * 3 * 4));
    float* ea2 = (float*)(ws + alloc((size_t)E_N * 2 * 4));
    char* PQ = (char*)(ws + alloc((size_t)V_N * PQ_STRIDE));
    float* agg = (float*)(ws + alloc((size_t)V_N * 128 * 4));
    float* xagg = (float*)(ws + alloc((size_t)V_N * 3 * 4));
    bf16* projT = (bf16*)(ws + alloc(2 * 256 * 128 * 2));
    bf16* ew2T = (bf16*)(ws + alloc(2 * 128 * 128 * 2));
    bf16* nw1T = (bf16*)(ws + alloc(2 * 128 * 256 * 2));
    bf16* nw2T = (bf16*)(ws + alloc(2 * 128 * 128 * 2));
    bf16* cprojT = (bf16*)(ws + alloc(256 * 128 * 2));
    bf16* cw2T = (bf16*)(ws + alloc(128 * 128 * 2));
    float* biasPQ = (float*)(ws + alloc(2 * 256 * 4));
    float* biasCPQ = (float*)(ws + alloc(256 * 4));
    int* cnt = (int*)(ws + alloc((size_t)V_N * 4));
    int* offv = (int*)(ws + alloc((size_t)V_N * 4));
    int* srow = (int*)(ws + alloc((size_t)E_N * 4));
    int* scol = (int*)(ws + alloc((size_t)E_N * 4));
    int* perm = (int*)(ws + alloc((size_t)E_N * 4));

    float* outh = (float*)d_out;
    float* outx = outh + (size_t)V_N * 128;

    hipMemcpyAsync(outh, h, (size_t)V_N * 128 * 4, hipMemcpyDeviceToDevice, stream);
    k_weights<<<964, 256, 0, stream>>>(ew1, ew2, nw1, nw2, cw1, cw2, eb1, cb1,
                                       projT, ew2T, nw1T, nw2T, cprojT, cw2T,
                                       biasPQ, biasCPQ);
    // counting sort of edges by row
    hipMemsetAsync(cnt, 0, (size_t)V_N * 4, stream);
    k_hist<<<(E_N + 255) / 256, 256, 0, stream>>>(ei, cnt);
    k_scan<<<1, 1024, 0, stream>>>(cnt, offv);
    k_scatter<<<(E_N + 255) / 256, 256, 0, stream>>>(ei, offv, srow, scol, perm);
    k_edgeprep2<<<(E_N + 255) / 256, 256, 0, stream>>>(perm, srow, scol, x, eattr, cd, ea2);
    hipMemsetAsync(xagg, 0, (size_t)V_N * 3 * 4, stream);
    hipMemsetAsync(agg, 0, (size_t)V_N * 128 * 4, stream);

    int mblocks = (V_N + 63) / 64;
    // layer 0: standalone projection (bias-folded)
    dim3 gproj(mblocks, 2);
    k_node_gemm<<<gproj, 256, 0, stream>>>(outh, nullptr, projT, biasPQ, nullptr,
                                           (float*)PQ, V_N, 128, 256, 0, 1);
    k_edge_gcl<<<512, 512, 0, stream>>>(
        srow, scol, PQ, ea2, ew1 + 256 * 128,
        ew2T, eb2, aw, ab, agg);
    // node MLP 0 (zeroes agg in place) + fused projection for layer 1
    k_node_mlp<<<mblocks, 256, 0, stream>>>(agg, nw1T, nb1, nw2T, nb2, outh, V_N, 1,
                                            projT + 256 * 128, biasPQ + 256, PQ);
    k_edge_gcl<<<512, 512, 0, stream>>>(
        srow, scol, PQ, ea2, ew1 + (size_t)1 * 258 * 128 + 256 * 128,
        ew2T + 128 * 128, eb2 + 128, aw + 128, ab + 1, agg);
    // node MLP 1 + fused coord projection
    k_node_mlp<<<mblocks, 256, 0, stream>>>(agg, nw1T + 128 * 256, nb1 + 128,
                                            nw2T + 128 * 128, nb2 + 128, outh, V_N, 0,
                                            cprojT, biasCPQ, PQ);
    k_edge_coord<<<512, 512, 0, stream>>>(srow, scol, PQ, ea2, cw1 + 256 * 128,
                                          cw2T, cb2, cw3, cd, xagg);
    k_finalx<<<(V_N * 3 + 255) / 256, 256, 0, stream>>>(x, xagg, outx);
}

// Round 15
// 729.052 us; speedup vs baseline: 1.0514x; 1.0192x over previous
//
#include <hip/hip_runtime.h>

#define V_N 50000
#define E_N 800000
#define H_N 128

typedef __bf16 bf16;
typedef bf16 bf16x4 __attribute__((ext_vector_type(4)));
typedef bf16 bf16x8 __attribute__((ext_vector_type(8)));
typedef float f32x4 __attribute__((ext_vector_type(4)));

// PQ all-bf16 row layout: 512 bytes/node = 128 bf16 (P, bias-folded) + 128 bf16 (Q)
#define PQ_STRIDE 512

// Fast silu/sigmoid: v_rcp_f32 instead of the IEEE divide sequence.
__device__ __forceinline__ float silu_f(float x) {
    return x * __builtin_amdgcn_rcpf(1.0f + __expf(-x));
}
__device__ __forceinline__ float sigmoid_f(float x) {
    return __builtin_amdgcn_rcpf(1.0f + __expf(-x));
}

// ---------------------------------------------------------------------------
// Weight prep: transpose all GEMM weights to [N][K] bf16 + build PQ bias
// tables (eb1/cb1 folded into the P half of the projection output).
// ---------------------------------------------------------------------------
__global__ void k_weights(const float* __restrict__ ew1, const float* __restrict__ ew2,
                          const float* __restrict__ nw1, const float* __restrict__ nw2,
                          const float* __restrict__ cw1, const float* __restrict__ cw2,
                          const float* __restrict__ eb1, const float* __restrict__ cb1,
                          bf16* __restrict__ projT, bf16* __restrict__ ew2T,
                          bf16* __restrict__ nw1T, bf16* __restrict__ nw2T,
                          bf16* __restrict__ cprojT, bf16* __restrict__ cw2T,
                          float* __restrict__ biasPQ, float* __restrict__ biasCPQ) {
    int idx = blockIdx.x * 256 + threadIdx.x;
    if (idx < 65536) {                       // projT: 2 layers x [256][128]
        int l = idx >> 15, rem = idx & 32767;
        int n = rem >> 7, k = rem & 127;
        const float* W = ew1 + l * 258 * 128;
        projT[idx] = (bf16)((n < 128) ? W[k * 128 + n] : W[(128 + k) * 128 + (n - 128)]);
    } else if (idx < 98304) {                // ew2T: 2 x [128][128]
        int r = idx - 65536;
        int l = r >> 14, rem = r & 16383;
        int n = rem >> 7, k = rem & 127;
        ew2T[r] = (bf16)(ew2[l * 16384 + k * 128 + n]);
    } else if (idx < 163840) {               // nw1T: 2 x [128][256]
        int r = idx - 98304;
        int l = r >> 15, rem = r & 32767;
        int n = rem >> 8, k = rem & 255;
        nw1T[r] = (bf16)(nw1[l * 32768 + k * 128 + n]);
    } else if (idx < 196608) {               // nw2T: 2 x [128][128]
        int r = idx - 163840;
        int l = r >> 14, rem = r & 16383;
        int n = rem >> 7, k = rem & 127;
        nw2T[r] = (bf16)(nw2[l * 16384 + k * 128 + n]);
    } else if (idx < 229376) {               // cprojT: [256][128]
        int r = idx - 196608;
        int n = r >> 7, k = r & 127;
        cprojT[r] = (bf16)((n < 128) ? cw1[k * 128 + n] : cw1[(128 + k) * 128 + (n - 128)]);
    } else if (idx < 245760) {               // cw2T: [128][128]
        int r = idx - 229376;
        int n = r >> 7, k = r & 127;
        cw2T[r] = (bf16)(cw2[k * 128 + n]);
    } else if (idx < 246272) {               // biasPQ: 2 layers x [256]
        int r = idx - 245760;
        int l = r >> 8, c = r & 255;
        biasPQ[r] = (c < 128) ? eb1[l * 128 + c] : 0.0f;
    } else if (idx < 246528) {               // biasCPQ: [256]
        int c = idx - 246272;
        biasCPQ[c] = (c < 128) ? cb1[c] : 0.0f;
    }
}

// ---------------------------------------------------------------------------
// Counting sort of edges by destination row (ei[0][e]).
// ---------------------------------------------------------------------------
__global__ void k_hist(const int* __restrict__ ei, int* __restrict__ cnt) {
    int e = blockIdx.x * 256 + threadIdx.x;
    if (e < E_N) atomicAdd(&cnt[ei[e]], 1);
}

__global__ __launch_bounds__(1024) void k_scan(const int* __restrict__ cnt,
                                               int* __restrict__ off) {
    __shared__ int wsum[16];
    __shared__ int wscan[16];
    __shared__ int carry_s;
    int tid = threadIdx.x;
    int lane = tid & 63, wid = tid >> 6;
    if (tid == 0) carry_s = 0;
    __syncthreads();
    for (int base = 0; base < V_N; base += 1024) {
        int carry = carry_s;
        int i = base + tid;
        int v = (i < V_N) ? cnt[i] : 0;
        int val = v;
#pragma unroll
        for (int d = 1; d < 64; d <<= 1) {
            int t = __shfl_up(val, d, 64);
            if (lane >= d) val += t;
        }
        if (lane == 63) wsum[wid] = val;
        __syncthreads();
        if (tid == 0) {
            int s = 0;
#pragma unroll
            for (int k = 0; k < 16; k++) { s += wsum[k]; wscan[k] = s; }
        }
        __syncthreads();
        int wbase = wid ? wscan[wid - 1] : 0;
        if (i < V_N) off[i] = carry + wbase + val - v;
        __syncthreads();
        if (tid == 0) carry_s = carry + wscan[15];
        __syncthreads();
    }
}

__global__ void k_scatter(const int* __restrict__ ei, int* __restrict__ off,
                          int* __restrict__ srow, int* __restrict__ scol,
                          int* __restrict__ perm) {
    int e = blockIdx.x * 256 + threadIdx.x;
    if (e >= E_N) return;
    int r = ei[e], c = ei[E_N + e];
    int p = atomicAdd(&off[r], 1);
    srow[p] = r;
    scol[p] = c;
    perm[p] = e;
}

__global__ void k_edgeprep2(const int* __restrict__ perm, const int* __restrict__ srow,
                            const int* __restrict__ scol, const float* __restrict__ x,
                            const float* __restrict__ eattr,
                            float* __restrict__ cd, float* __restrict__ ea2) {
    int p = blockIdx.x * 256 + threadIdx.x;
    if (p >= E_N) return;
    int e = perm[p];
    int r = srow[p], c = scol[p];
    float dx = x[r * 3 + 0] - x[c * 3 + 0];
    float dy = x[r * 3 + 1] - x[c * 3 + 1];
    float dz = x[r * 3 + 2] - x[c * 3 + 2];
    float rad = dx * dx + dy * dy + dz * dz;
    float inv = 1.0f / (sqrtf(rad + 1e-8f) + 1.0f);
    cd[p * 3 + 0] = dx * inv;
    cd[p * 3 + 1] = dy * inv;
    cd[p * 3 + 2] = dz * inv;
    ea2[p * 2 + 0] = rad;
    ea2[p * 2 + 1] = eattr[e];
}

// ---------------------------------------------------------------------------
// Generic node-level GEMM. opq=1 writes the all-bf16 PQ layout (512B rows).
// ---------------------------------------------------------------------------
__global__ __launch_bounds__(256) void k_node_gemm(
    const float* __restrict__ A1, const float* __restrict__ A2,
    const bf16* __restrict__ BT, const float* __restrict__ bias,
    const float* __restrict__ resid, float* __restrict__ C,
    int M, int K, int Ntot, int act, int opq) {
    __shared__ __align__(16) bf16 Asl[64][136];
    __shared__ __align__(16) bf16 Bsl[128][136];
    int tid = threadIdx.x;
    int m0 = blockIdx.x * 64;
    int n0 = blockIdx.y * 128;
    int lane = tid & 63, w = tid >> 6;
    int q = lane >> 4, l15 = lane & 15;

    f32x4 acc[8];
#pragma unroll
    for (int i = 0; i < 8; i++) acc[i] = (f32x4){0.f, 0.f, 0.f, 0.f};

    for (int kc = 0; kc < K; kc += 128) {
        const float* Asrc = (kc == 0) ? A1 : A2;
#pragma unroll
        for (int p = 0; p < 8; p++) {
            int e4 = (p * 256 + tid) * 4;
            int r = e4 >> 7, k = e4 & 127;
            float4 v = {0.f, 0.f, 0.f, 0.f};
            int row = m0 + r;
            if (row < M) v = *(const float4*)&Asrc[(size_t)row * 128 + k];
            bf16x4 b4 = {(bf16)v.x, (bf16)v.y, (bf16)v.z, (bf16)v.w};
            *(bf16x4*)&Asl[r][k] = b4;
        }
#pragma unroll
        for (int p = 0; p < 8; p++) {
            int e8 = (p * 256 + tid) * 8;
            int n = e8 >> 7, k = e8 & 127;
            bf16x8 v = *(const bf16x8*)&BT[(size_t)(n0 + n) * K + kc + k];
            *(bf16x8*)&Bsl[n][k] = v;
        }
        __syncthreads();
        int ar = w * 16 + l15;
#pragma unroll
        for (int kt = 0; kt < 4; kt++) {
            bf16x8 a = *(const bf16x8*)&Asl[ar][kt * 32 + q * 8];
#pragma unroll
            for (int nt = 0; nt < 8; nt++) {
                bf16x8 b = *(const bf16x8*)&Bsl[nt * 16 + l15][kt * 32 + q * 8];
                acc[nt] = __builtin_amdgcn_mfma_f32_16x16x32_bf16(a, b, acc[nt], 0, 0, 0);
            }
        }
        __syncthreads();
    }
#pragma unroll
    for (int nt = 0; nt < 8; nt++) {
        int col = n0 + nt * 16 + l15;
        float bv = bias ? bias[col] : 0.0f;
#pragma unroll
        for (int reg = 0; reg < 4; reg++) {
            int row = m0 + w * 16 + q * 4 + reg;
            if (row < M) {
                float v = acc[nt][reg] + bv;
                if (act) v = silu_f(v);
                if (resid) v += resid[(size_t)row * 128 + (col & 127)];
                if (opq) {
                    *(bf16*)((char*)C + (size_t)row * PQ_STRIDE + col * 2) = (bf16)v;
                } else {
                    C[(size_t)row * Ntot + col] = v;
                }
            }
        }
    }
}

// ---------------------------------------------------------------------------
// Fused node MLP + next projection.
// ---------------------------------------------------------------------------
__global__ __launch_bounds__(256) void k_node_mlp(
    float* __restrict__ A2,             // agg (zeroed in place if zeroA2)
    const bf16* __restrict__ B1T,       // nw1T [128][256]
    const float* __restrict__ b1,
    const bf16* __restrict__ B2T,       // nw2T [128][128]
    const float* __restrict__ b2,
    float* __restrict__ H,              // outh, in/out
    int M, int zeroA2,
    const bf16* __restrict__ PT,        // next proj [256][128]
    const float* __restrict__ pbias,    // 256 (eb1 in P half, 0 in Q half)
    char* __restrict__ PQout) {
    __shared__ __align__(16) bf16 Asl[64][136];
    __shared__ __align__(16) bf16 Bsl[128][136];
    int tid = threadIdx.x;
    int m0 = blockIdx.x * 64;
    int lane = tid & 63, w = tid >> 6;
    int q = lane >> 4, l15 = lane & 15;
    int ar = w * 16 + l15;

    f32x4 acc[8];
#pragma unroll
    for (int i = 0; i < 8; i++) acc[i] = (f32x4){0.f, 0.f, 0.f, 0.f};

    for (int kc = 0; kc < 256; kc += 128) {
        const float* Asrc = (kc == 0) ? H : A2;
#pragma unroll
        for (int p = 0; p < 8; p++) {
            int e4 = (p * 256 + tid) * 4;
            int r = e4 >> 7, k = e4 & 127;
            float4 v = {0.f, 0.f, 0.f, 0.f};
            int row = m0 + r;
            if (row < M) v = *(const float4*)&Asrc[(size_t)row * 128 + k];
            bf16x4 b4 = {(bf16)v.x, (bf16)v.y, (bf16)v.z, (bf16)v.w};
            *(bf16x4*)&Asl[r][k] = b4;
            if (kc == 128 && zeroA2 && row < M) {
                *(float4*)&A2[(size_t)row * 128 + k] = (float4){0.f, 0.f, 0.f, 0.f};
            }
        }
#pragma unroll
        for (int p = 0; p < 8; p++) {
            int e8 = (p * 256 + tid) * 8;
            int n = e8 >> 7, k = e8 & 127;
            bf16x8 v = *(const bf16x8*)&B1T[(size_t)n * 256 + kc + k];
            *(bf16x8*)&Bsl[n][k] = v;
        }
        __syncthreads();
#pragma unroll
        for (int kt = 0; kt < 4; kt++) {
            bf16x8 a = *(const bf16x8*)&Asl[ar][kt * 32 + q * 8];
#pragma unroll
            for (int nt = 0; nt < 8; nt++) {
                bf16x8 b = *(const bf16x8*)&Bsl[nt * 16 + l15][kt * 32 + q * 8];
                acc[nt] = __builtin_amdgcn_mfma_f32_16x16x32_bf16(a, b, acc[nt], 0, 0, 0);
            }
        }
        __syncthreads();
    }
#pragma unroll
    for (int nt = 0; nt < 8; nt++) {
        float bv = b1[nt * 16 + l15];
#pragma unroll
        for (int reg = 0; reg < 4; reg++) {
            int r = w * 16 + q * 4 + reg;
            Asl[r][nt * 16 + l15] = (bf16)silu_f(acc[nt][reg] + bv);
        }
    }
#pragma unroll
    for (int p = 0; p < 8; p++) {
        int e8 = (p * 256 + tid) * 8;
        int n = e8 >> 7, k = e8 & 127;
        *(bf16x8*)&Bsl[n][k] = *(const bf16x8*)&B2T[(size_t)n * 128 + k];
    }
    __syncthreads();
    f32x4 acc2[8];
#pragma unroll
    for (int i = 0; i < 8; i++) acc2[i] = (f32x4){0.f, 0.f, 0.f, 0.f};
#pragma unroll
    for (int kt = 0; kt < 4; kt++) {
        bf16x8 a = *(const bf16x8*)&Asl[ar][kt * 32 + q * 8];
#pragma unroll
        for (int nt = 0; nt < 8; nt++) {
            bf16x8 b = *(const bf16x8*)&Bsl[nt * 16 + l15][kt * 32 + q * 8];
            acc2[nt] = __builtin_amdgcn_mfma_f32_16x16x32_bf16(a, b, acc2[nt], 0, 0, 0);
        }
    }
    // residual add -> Hnew (kept in acc2)
#pragma unroll
    for (int nt = 0; nt < 8; nt++) {
        int col = nt * 16 + l15;
        float bv = b2[col];
#pragma unroll
        for (int reg = 0; reg < 4; reg++) {
            int row = m0 + w * 16 + q * 4 + reg;
            if (row < M) {
                float hv = H[(size_t)row * 128 + col] + acc2[nt][reg] + bv;
                H[(size_t)row * 128 + col] = hv;
                acc2[nt][reg] = hv;
            }
        }
    }
    __syncthreads();   // all GEMM2 LDS reads done
#pragma unroll
    for (int nt = 0; nt < 8; nt++) {
#pragma unroll
        for (int reg = 0; reg < 4; reg++) {
            int r = w * 16 + q * 4 + reg;
            Asl[r][nt * 16 + l15] = (bf16)acc2[nt][reg];
        }
    }
    // fused projection: PQ = Hnew @ PT + pbias, two 128-col halves
    for (int half = 0; half < 2; half++) {
#pragma unroll
        for (int p = 0; p < 8; p++) {
            int e8 = (p * 256 + tid) * 8;
            int n = e8 >> 7, k = e8 & 127;
            *(bf16x8*)&Bsl[n][k] = *(const bf16x8*)&PT[(size_t)(half * 128 + n) * 128 + k];
        }
        __syncthreads();
        f32x4 accp[8];
#pragma unroll
        for (int i = 0; i < 8; i++) accp[i] = (f32x4){0.f, 0.f, 0.f, 0.f};
#pragma unroll
        for (int kt = 0; kt < 4; kt++) {
            bf16x8 a = *(const bf16x8*)&Asl[ar][kt * 32 + q * 8];
#pragma unroll
            for (int nt = 0; nt < 8; nt++) {
                bf16x8 b = *(const bf16x8*)&Bsl[nt * 16 + l15][kt * 32 + q * 8];
                accp[nt] = __builtin_amdgcn_mfma_f32_16x16x32_bf16(a, b, accp[nt], 0, 0, 0);
            }
        }
#pragma unroll
        for (int nt = 0; nt < 8; nt++) {
            int colg = half * 128 + nt * 16 + l15;
            float bv = pbias[colg];
#pragma unroll
            for (int reg = 0; reg < 4; reg++) {
                int row = m0 + w * 16 + q * 4 + reg;
                if (row < M) {
                    *(bf16*)(PQout + (size_t)row * PQ_STRIDE + colg * 2) =
                        (bf16)(accp[nt][reg] + bv);
                }
            }
        }
        __syncthreads();
    }
}

// ---------------------------------------------------------------------------
// Persistent fused GCL edge kernel: 512 threads, 128 sorted edges/tile.
// WAVE-PRIVATE stage-A: wave w stages its own 16 edges (4 passes x 4 edges,
// 16 lanes x 16B per edge -> coalescing identical to block-wide version),
// so staging->MFMA is intra-wave and needs NO barrier. 2 barriers/tile.
// ---------------------------------------------------------------------------
#define NTILES (E_N / 128)

__global__ __launch_bounds__(512, 4) void k_edge_gcl(
    const int* __restrict__ srow, const int* __restrict__ scol,
    const char* __restrict__ PQ,
    const float* __restrict__ ea2, const float* __restrict__ w1c,
    const bf16* __restrict__ ew2T,
    const float* __restrict__ eb2, const float* __restrict__ aw,
    const float* __restrict__ ab, float* __restrict__ agg) {
    __shared__ __align__(16) bf16 Asl[128][136];   // A-tile; overlaid as FslT[col][edge]
    __shared__ __align__(16) bf16 Bsl[128][136];   // persistent weight tile
    __shared__ int rows_s[2][128];
    __shared__ int cols_s[2][128];
    __shared__ float ra_s[2][128], aa_s[2][128];
    int tid = threadIdx.x;
    int lane = tid & 63, w = tid >> 6, q = lane >> 4, l15 = lane & 15;
    int j8 = l15 * 8;          // fixed 8-column group per lane
    int eg4 = lane >> 4;       // edge-in-pass within this wave (0..3)

    // stage B once
#pragma unroll
    for (int p = 0; p < 4; p++) {
        int e8 = (p * 512 + tid) * 8;
        int n = e8 >> 7, k = e8 & 127;
        *(bf16x8*)&Bsl[n][k] = *(const bf16x8*)&ew2T[n * 128 + k];
    }
    float4 w0a = *(const float4*)&w1c[j8];
    float4 w0b = *(const float4*)&w1c[j8 + 4];
    float4 w1a = *(const float4*)&w1c[128 + j8];
    float4 w1b = *(const float4*)&w1c[128 + j8 + 4];
    float b2v[8], awv[8];
#pragma unroll
    for (int nt = 0; nt < 8; nt++) {
        b2v[nt] = eb2[nt * 16 + l15];
        awv[nt] = aw[nt * 16 + l15];
    }
    float ab0 = ab[0];

    // prologue: stage meta(t0) into buffer 0
    int t0 = blockIdx.x;
    if (tid < 128) {
        int e = t0 * 128 + tid;
        rows_s[0][tid] = srow[e];
        cols_s[0][tid] = scol[e];
        float2 rr = *(const float2*)&ea2[(size_t)e * 2];
        ra_s[0][tid] = rr.x;
        aa_s[0][tid] = rr.y;
    }

    int b = 0;
    for (int t = t0; t < NTILES; t += gridDim.x, b ^= 1) {
        int tn = t + gridDim.x;
        __syncthreads();   // B1: prev reduce done; meta[b] visible
        if (tn < NTILES && tid < 128) {
            int e = tn * 128 + tid;
            rows_s[b ^ 1][tid] = srow[e];
            cols_s[b ^ 1][tid] = scol[e];
            float2 rr = *(const float2*)&ea2[(size_t)e * 2];
            ra_s[b ^ 1][tid] = rr.x;
            aa_s[b ^ 1][tid] = rr.y;
        }
        // stage A (wave-private): 4 passes x 4 edges of THIS wave's 16 edges
        bf16x8 pb[4];
        bf16x8 qb[4];
#pragma unroll
        for (int p = 0; p < 4; p++) {
            int el = w * 16 + p * 4 + eg4;
            int row = rows_s[b][el], col = cols_s[b][el];
            pb[p] = *(const bf16x8*)(PQ + (size_t)row * PQ_STRIDE + j8 * 2);
            qb[p] = *(const bf16x8*)(PQ + (size_t)col * PQ_STRIDE + 256 + j8 * 2);
        }
#pragma unroll
        for (int p = 0; p < 4; p++) {
            int el = w * 16 + p * 4 + eg4;
            float ra = ra_s[b][el], aa = aa_s[b][el];
            bf16x8 m8;
            float z;
            z = (float)pb[p][0] + (float)qb[p][0]; z = fmaf(aa, w1a.x, fmaf(ra, w0a.x, z)); m8[0] = (bf16)silu_f(z);
            z = (float)pb[p][1] + (float)qb[p][1]; z = fmaf(aa, w1a.y, fmaf(ra, w0a.y, z)); m8[1] = (bf16)silu_f(z);
            z = (float)pb[p][2] + (float)qb[p][2]; z = fmaf(aa, w1a.z, fmaf(ra, w0a.z, z)); m8[2] = (bf16)silu_f(z);
            z = (float)pb[p][3] + (float)qb[p][3]; z = fmaf(aa, w1a.w, fmaf(ra, w0a.w, z)); m8[3] = (bf16)silu_f(z);
            z = (float)pb[p][4] + (float)qb[p][4]; z = fmaf(aa, w1b.x, fmaf(ra, w0b.x, z)); m8[4] = (bf16)silu_f(z);
            z = (float)pb[p][5] + (float)qb[p][5]; z = fmaf(aa, w1b.y, fmaf(ra, w0b.y, z)); m8[5] = (bf16)silu_f(z);
            z = (float)pb[p][6] + (float)qb[p][6]; z = fmaf(aa, w1b.z, fmaf(ra, w0b.z, z)); m8[6] = (bf16)silu_f(z);
            z = (float)pb[p][7] + (float)qb[p][7]; z = fmaf(aa, w1b.w, fmaf(ra, w0b.w, z)); m8[7] = (bf16)silu_f(z);
            *(bf16x8*)&Asl[el][j8] = m8;
        }
        // no barrier: wave w only reads rows w*16..w*16+15 (written above)
        f32x4 acc[8];
#pragma unroll
        for (int i = 0; i < 8; i++) acc[i] = (f32x4){0.f, 0.f, 0.f, 0.f};
        int ar = w * 16 + l15;
#pragma unroll
        for (int kt = 0; kt < 4; kt++) {
            bf16x8 a = *(const bf16x8*)&Asl[ar][kt * 32 + q * 8];
#pragma unroll
            for (int nt = 0; nt < 8; nt++) {
                bf16x8 bb = *(const bf16x8*)&Bsl[nt * 16 + l15][kt * 32 + q * 8];
                acc[nt] = __builtin_amdgcn_mfma_f32_16x16x32_bf16(a, bb, acc[nt], 0, 0, 0);
            }
        }
        // epilogue in regs: silu + attention dot
        float partial[4] = {0.f, 0.f, 0.f, 0.f};
#pragma unroll
        for (int nt = 0; nt < 8; nt++) {
#pragma unroll
            for (int reg = 0; reg < 4; reg++) {
                float mv = silu_f(acc[nt][reg] + b2v[nt]);
                acc[nt][reg] = mv;
                partial[reg] += mv * awv[nt];
            }
        }
        float scale[4];
#pragma unroll
        for (int reg = 0; reg < 4; reg++) {
            float s = partial[reg];
            s += __shfl_xor(s, 1, 16);
            s += __shfl_xor(s, 2, 16);
            s += __shfl_xor(s, 4, 16);
            s += __shfl_xor(s, 8, 16);
            scale[reg] = sigmoid_f(s + ab0) * 0.01f;
        }
        __syncthreads();   // B4: all MFMA reads of Asl done -> overlay FslT
        // FslT[col][edge], full 136 stride (collision-free); wave w writes
        // only its edge-columns er=w*16.., reads only those back.
#pragma unroll
        for (int reg = 0; reg < 4; reg++) {
            int er = w * 16 + q * 4 + reg;
            float sc = scale[reg];
#pragma unroll
            for (int nt = 0; nt < 8; nt++) {
                Asl[nt * 16 + l15][er] = (bf16)(acc[nt][reg] * sc);
            }
        }
        // wave-private reduce: read back ONLY this wave's 16-edge range.
        int c0 = lane, c1 = lane + 64;
        int eb = w * 16;
        bf16x8 f0a = *(const bf16x8*)&Asl[c0][eb];
        bf16x8 f0b = *(const bf16x8*)&Asl[c0][eb + 8];
        bf16x8 f1a = *(const bf16x8*)&Asl[c1][eb];
        bf16x8 f1b = *(const bf16x8*)&Asl[c1][eb + 8];
        float s0 = 0.f, s1 = 0.f;
#pragma unroll
        for (int el = 0; el < 16; ++el) {
            float v0 = (el < 8) ? (float)f0a[el & 7] : (float)f0b[el & 7];
            float v1 = (el < 8) ? (float)f1a[el & 7] : (float)f1b[el & 7];
            s0 += v0;
            s1 += v1;
            int r = rows_s[b][eb + el];
            int nxt = (el < 15) ? rows_s[b][eb + el + 1] : -1;
            if (r != nxt) {
                atomicAdd(&agg[(size_t)r * 128 + c0], s0);
                atomicAdd(&agg[(size_t)r * 128 + c1], s1);
                s0 = 0.f;
                s1 = 0.f;
            }
        }
    }
}

// ---------------------------------------------------------------------------
// Persistent fused coord-update edge kernel: wave-private stage-A + Ssl
// reduce -> 1 barrier/tile.
// ---------------------------------------------------------------------------
__global__ __launch_bounds__(512, 4) void k_edge_coord(
    const int* __restrict__ srow, const int* __restrict__ scol,
    const char* __restrict__ PQ,
    const float* __restrict__ ea2, const float* __restrict__ c1c,
    const bf16* __restrict__ cw2T,
    const float* __restrict__ cb2, const float* __restrict__ cw3,
    const float* __restrict__ cd, float* __restrict__ xagg) {
    __shared__ __align__(16) bf16 Asl[128][136];
    __shared__ __align__(16) bf16 Bsl[128][136];
    __shared__ int rows_s[2][128];
    __shared__ int cols_s[2][128];
    __shared__ float ra_s[2][128], aa_s[2][128];
    __shared__ float cds[2][384];
    __shared__ float Ssl[128];
    int tid = threadIdx.x;
    int lane = tid & 63, w = tid >> 6, q = lane >> 4, l15 = lane & 15;
    int j8 = l15 * 8;
    int eg4 = lane >> 4;

#pragma unroll
    for (int p = 0; p < 4; p++) {
        int e8 = (p * 512 + tid) * 8;
        int n = e8 >> 7, k = e8 & 127;
        *(bf16x8*)&Bsl[n][k] = *(const bf16x8*)&cw2T[n * 128 + k];
    }
    float4 w0a = *(const float4*)&c1c[j8];
    float4 w0b = *(const float4*)&c1c[j8 + 4];
    float4 w1a = *(const float4*)&c1c[128 + j8];
    float4 w1b = *(const float4*)&c1c[128 + j8 + 4];
    float b2v[8], w3v[8];
#pragma unroll
    for (int nt = 0; nt < 8; nt++) {
        b2v[nt] = cb2[nt * 16 + l15];
        w3v[nt] = cw3[nt * 16 + l15];
    }

    int t0 = blockIdx.x;
    if (tid < 128) {
        int e = t0 * 128 + tid;
        rows_s[0][tid] = srow[e];
        cols_s[0][tid] = scol[e];
        float2 rr = *(const float2*)&ea2[(size_t)e * 2];
        ra_s[0][tid] = rr.x;
        aa_s[0][tid] = rr.y;
    }
    if (tid < 384) cds[0][tid] = cd[(size_t)t0 * 384 + tid];

    int b = 0;
    for (int t = t0; t < NTILES; t += gridDim.x, b ^= 1) {
        int tn = t + gridDim.x;
        __syncthreads();   // B1
        if (tn < NTILES) {
            if (tid < 128) {
                int e = tn * 128 + tid;
                rows_s[b ^ 1][tid] = srow[e];
                cols_s[b ^ 1][tid] = scol[e];
                float2 rr = *(const float2*)&ea2[(size_t)e * 2];
                ra_s[b ^ 1][tid] = rr.x;
                aa_s[b ^ 1][tid] = rr.y;
            }
            if (tid < 384) cds[b ^ 1][tid] = cd[(size_t)tn * 384 + tid];
        }
        bf16x8 pb[4];
        bf16x8 qb[4];
#pragma unroll
        for (int p = 0; p < 4; p++) {
            int el = w * 16 + p * 4 + eg4;
            int row = rows_s[b][el], col = cols_s[b][el];
            pb[p] = *(const bf16x8*)(PQ + (size_t)row * PQ_STRIDE + j8 * 2);
            qb[p] = *(const bf16x8*)(PQ + (size_t)col * PQ_STRIDE + 256 + j8 * 2);
        }
#pragma unroll
        for (int p = 0; p < 4; p++) {
            int el = w * 16 + p * 4 + eg4;
            float ra = ra_s[b][el], aa = aa_s[b][el];
            bf16x8 m8;
            float z;
            z = (float)pb[p][0] + (float)qb[p][0]; z = fmaf(aa, w1a.x, fmaf(ra, w0a.x, z)); m8[0] = (bf16)silu_f(z);
            z = (float)pb[p][1] + (float)qb[p][1]; z = fmaf(aa, w1a.y, fmaf(ra, w0a.y, z)); m8[1] = (bf16)silu_f(z);
            z = (float)pb[p][2] + (float)qb[p][2]; z = fmaf(aa, w1a.z, fmaf(ra, w0a.z, z)); m8[2] = (bf16)silu_f(z);
            z = (float)pb[p][3] + (float)qb[p][3]; z = fmaf(aa, w1a.w, fmaf(ra, w0a.w, z)); m8[3] = (bf16)silu_f(z);
            z = (float)pb[p][4] + (float)qb[p][4]; z = fmaf(aa, w1b.x, fmaf(ra, w0b.x, z)); m8[4] = (bf16)silu_f(z);
            z = (float)pb[p][5] + (float)qb[p][5]; z = fmaf(aa, w1b.y, fmaf(ra, w0b.y, z)); m8[5] = (bf16)silu_f(z);
            z = (float)pb[p][6] + (float)qb[p][6]; z = fmaf(aa, w1b.z, fmaf(ra, w0b.z, z)); m8[6] = (bf16)silu_f(z);
            z = (float)pb[p][7] + (float)qb[p][7]; z = fmaf(aa, w1b.w, fmaf(ra, w0b.w, z)); m8[7] = (bf16)silu_f(z);
            *(bf16x8*)&Asl[el][j8] = m8;
        }
        // no barrier: wave-private rows
        f32x4 acc[8];
#pragma unroll
        for (int i = 0; i < 8; i++) acc[i] = (f32x4){0.f, 0.f, 0.f, 0.f};
        int ar = w * 16 + l15;
#pragma unroll
        for (int kt = 0; kt < 4; kt++) {
            bf16x8 a = *(const bf16x8*)&Asl[ar][kt * 32 + q * 8];
#pragma unroll
            for (int nt = 0; nt < 8; nt++) {
                bf16x8 bb = *(const bf16x8*)&Bsl[nt * 16 + l15][kt * 32 + q * 8];
                acc[nt] = __builtin_amdgcn_mfma_f32_16x16x32_bf16(a, bb, acc[nt], 0, 0, 0);
            }
        }
        float partial[4] = {0.f, 0.f, 0.f, 0.f};
#pragma unroll
        for (int nt = 0; nt < 8; nt++) {
#pragma unroll
            for (int reg = 0; reg < 4; reg++) {
                float tv = silu_f(acc[nt][reg] + b2v[nt]);
                partial[reg] += tv * w3v[nt];
            }
        }
#pragma unroll
        for (int reg = 0; reg < 4; reg++) {
            float s = partial[reg];
            s += __shfl_xor(s, 1, 16);
            s += __shfl_xor(s, 2, 16);
            s += __shfl_xor(s, 4, 16);
            s += __shfl_xor(s, 8, 16);
            if (l15 == 0) Ssl[w * 16 + q * 4 + reg] = s * 0.01f;
        }
        // wave-private segmented reduce (intra-wave Ssl, no barrier)
        if (lane < 3) {
            int d = lane;
            float sum = 0.f;
#pragma unroll
            for (int el = 0; el < 16; ++el) {
                int ge = w * 16 + el;
                sum += cds[b][ge * 3 + d] * Ssl[ge];
                int r = rows_s[b][ge];
                int nxt = (el < 15) ? rows_s[b][ge + 1] : -1;
                if (r != nxt) {
                    atomicAdd(&xagg[(size_t)r * 3 + d], sum);
                    sum = 0.f;
                }
            }
        }
    }
}

__global__ void k_finalx(const float* __restrict__ x, const float* __restrict__ xagg,
                         float* __restrict__ outx) {
    int i = blockIdx.x * 256 + threadIdx.x;
    if (i < V_N * 3) outx[i] = x[i] + xagg[i];
}

// ---------------------------------------------------------------------------
extern "C" void kernel_launch(void* const* d_in, const int* in_sizes, int n_in,
                              void* d_out, int out_size, void* d_ws, size_t ws_size,
                              hipStream_t stream) {
    const float* h = (const float*)d_in[0];
    const float* x = (const float*)d_in[1];
    const int* ei = (const int*)d_in[2];
    const float* eattr = (const float*)d_in[3];
    const float* ew1 = (const float*)d_in[4];
    const float* eb1 = (const float*)d_in[5];
    const float* ew2 = (const float*)d_in[6];
    const float* eb2 = (const float*)d_in[7];
    const float* aw = (const float*)d_in[8];
    const float* ab = (const float*)d_in[9];
    const float* nw1 = (const float*)d_in[10];
    const float* nb1 = (const float*)d_in[11];
    const float* nw2 = (const float*)d_in[12];
    const float* nb2 = (const float*)d_in[13];
    const float* cw1 = (const float*)d_in[14];
    const float* cb1 = (const float*)d_in[15];
    const float* cw2 = (const float*)d_in[16];
    const float* cb2 = (const float*)d_in[17];
    const float* cw3 = (const float*)d_in[18];

    char* ws = (char*)d_ws;
    size_t off_b = 0;
    auto alloc = [&](size_t b) {
        size_t o = off_b;
        off_b += (b + 255) & ~(size_t)255;
        return o;
    };
    float* cd = (float*)(ws + alloc((size_t)E_N * 3 * 4));
    float* ea2 = (float*)(ws + alloc((size_t)E_N * 2 * 4));
    char* PQ = (char*)(ws + alloc((size_t)V_N * PQ_STRIDE));
    float* agg = (float*)(ws + alloc((size_t)V_N * 128 * 4));
    float* xagg = (float*)(ws + alloc((size_t)V_N * 3 * 4));
    bf16* projT = (bf16*)(ws + alloc(2 * 256 * 128 * 2));
    bf16* ew2T = (bf16*)(ws + alloc(2 * 128 * 128 * 2));
    bf16* nw1T = (bf16*)(ws + alloc(2 * 128 * 256 * 2));
    bf16* nw2T = (bf16*)(ws + alloc(2 * 128 * 128 * 2));
    bf16* cprojT = (bf16*)(ws + alloc(256 * 128 * 2));
    bf16* cw2T = (bf16*)(ws + alloc(128 * 128 * 2));
    float* biasPQ = (float*)(ws + alloc(2 * 256 * 4));
    float* biasCPQ = (float*)(ws + alloc(256 * 4));
    int* cnt = (int*)(ws + alloc((size_t)V_N * 4));
    int* offv = (int*)(ws + alloc((size_t)V_N * 4));
    int* srow = (int*)(ws + alloc((size_t)E_N * 4));
    int* scol = (int*)(ws + alloc((size_t)E_N * 4));
    int* perm = (int*)(ws + alloc((size_t)E_N * 4));

    float* outh = (float*)d_out;
    float* outx = outh + (size_t)V_N * 128;

    hipMemcpyAsync(outh, h, (size_t)V_N * 128 * 4, hipMemcpyDeviceToDevice, stream);
    k_weights<<<964, 256, 0, stream>>>(ew1, ew2, nw1, nw2, cw1, cw2, eb1, cb1,
                                       projT, ew2T, nw1T, nw2T, cprojT, cw2T,
                                       biasPQ, biasCPQ);
    // counting sort of edges by row
    hipMemsetAsync(cnt, 0, (size_t)V_N * 4, stream);
    k_hist<<<(E_N + 255) / 256, 256, 0, stream>>>(ei, cnt);
    k_scan<<<1, 1024, 0, stream>>>(cnt, offv);
    k_scatter<<<(E_N + 255) / 256, 256, 0, stream>>>(ei, offv, srow, scol, perm);
    k_edgeprep2<<<(E_N + 255) / 256, 256, 0, stream>>>(perm, srow, scol, x, eattr, cd, ea2);
    hipMemsetAsync(xagg, 0, (size_t)V_N * 3 * 4, stream);
    hipMemsetAsync(agg, 0, (size_t)V_N * 128 * 4, stream);

    int mblocks = (V_N + 63) / 64;
    // layer 0: standalone projection (bias-folded)
    dim3 gproj(mblocks, 2);
    k_node_gemm<<<gproj, 256, 0, stream>>>(outh, nullptr, projT, biasPQ, nullptr,
                                           (float*)PQ, V_N, 128, 256, 0, 1);
    k_edge_gcl<<<512, 512, 0, stream>>>(
        srow, scol, PQ, ea2, ew1 + 256 * 128,
        ew2T, eb2, aw, ab, agg);
    // node MLP 0 (zeroes agg in place) + fused projection for layer 1
    k_node_mlp<<<mblocks, 256, 0, stream>>>(agg, nw1T, nb1, nw2T, nb2, outh, V_N, 1,
                                            projT + 256 * 128, biasPQ + 256, PQ);
    k_edge_gcl<<<512, 512, 0, stream>>>(
        srow, scol, PQ, ea2, ew1 + (size_t)1 * 258 * 128 + 256 * 128,
        ew2T + 128 * 128, eb2 + 128, aw + 128, ab + 1, agg);
    // node MLP 1 + fused coord projection
    k_node_mlp<<<mblocks, 256, 0, stream>>>(agg, nw1T + 128 * 256, nb1 + 128,
                                            nw2T + 128 * 128, nb2 + 128, outh, V_N, 0,
                                            cprojT, biasCPQ, PQ);
    k_edge_coord<<<512, 512, 0, stream>>>(srow, scol, PQ, ea2, cw1 + 256 * 128,
                                          cw2T, cb2, cw3, cd, xagg);
    k_finalx<<<(V_N * 3 + 255) / 256, 256, 0, stream>>>(x, xagg, outx);
}

// Round 16
// 727.533 us; speedup vs baseline: 1.0536x; 1.0021x over previous
//
#include <hip/hip_runtime.h>

#define V_N 50000
#define E_N 800000
#define H_N 128

typedef __bf16 bf16;
typedef bf16 bf16x4 __attribute__((ext_vector_type(4)));
typedef bf16 bf16x8 __attribute__((ext_vector_type(8)));
typedef float f32x4 __attribute__((ext_vector_type(4)));

// PQ all-bf16 row layout: 512 bytes/node = 128 bf16 (P, bias-folded) + 128 bf16 (Q)
#define PQ_STRIDE 512

// Fast silu/sigmoid: v_rcp_f32 instead of the IEEE divide sequence.
__device__ __forceinline__ float silu_f(float x) {
    return x * __builtin_amdgcn_rcpf(1.0f + __expf(-x));
}
__device__ __forceinline__ float sigmoid_f(float x) {
    return __builtin_amdgcn_rcpf(1.0f + __expf(-x));
}

// ---------------------------------------------------------------------------
// Weight prep: transpose all GEMM weights to [N][K] bf16 + build PQ bias
// tables (eb1/cb1 folded into the P half of the projection output).
// ---------------------------------------------------------------------------
__global__ void k_weights(const float* __restrict__ ew1, const float* __restrict__ ew2,
                          const float* __restrict__ nw1, const float* __restrict__ nw2,
                          const float* __restrict__ cw1, const float* __restrict__ cw2,
                          const float* __restrict__ eb1, const float* __restrict__ cb1,
                          bf16* __restrict__ projT, bf16* __restrict__ ew2T,
                          bf16* __restrict__ nw1T, bf16* __restrict__ nw2T,
                          bf16* __restrict__ cprojT, bf16* __restrict__ cw2T,
                          float* __restrict__ biasPQ, float* __restrict__ biasCPQ) {
    int idx = blockIdx.x * 256 + threadIdx.x;
    if (idx < 65536) {                       // projT: 2 layers x [256][128]
        int l = idx >> 15, rem = idx & 32767;
        int n = rem >> 7, k = rem & 127;
        const float* W = ew1 + l * 258 * 128;
        projT[idx] = (bf16)((n < 128) ? W[k * 128 + n] : W[(128 + k) * 128 + (n - 128)]);
    } else if (idx < 98304) {                // ew2T: 2 x [128][128]
        int r = idx - 65536;
        int l = r >> 14, rem = r & 16383;
        int n = rem >> 7, k = rem & 127;
        ew2T[r] = (bf16)(ew2[l * 16384 + k * 128 + n]);
    } else if (idx < 163840) {               // nw1T: 2 x [128][256]
        int r = idx - 98304;
        int l = r >> 15, rem = r & 32767;
        int n = rem >> 8, k = rem & 255;
        nw1T[r] = (bf16)(nw1[l * 32768 + k * 128 + n]);
    } else if (idx < 196608) {               // nw2T: 2 x [128][128]
        int r = idx - 163840;
        int l = r >> 14, rem = r & 16383;
        int n = rem >> 7, k = rem & 127;
        nw2T[r] = (bf16)(nw2[l * 16384 + k * 128 + n]);
    } else if (idx < 229376) {               // cprojT: [256][128]
        int r = idx - 196608;
        int n = r >> 7, k = r & 127;
        cprojT[r] = (bf16)((n < 128) ? cw1[k * 128 + n] : cw1[(128 + k) * 128 + (n - 128)]);
    } else if (idx < 245760) {               // cw2T: [128][128]
        int r = idx - 229376;
        int n = r >> 7, k = r & 127;
        cw2T[r] = (bf16)(cw2[k * 128 + n]);
    } else if (idx < 246272) {               // biasPQ: 2 layers x [256]
        int r = idx - 245760;
        int l = r >> 8, c = r & 255;
        biasPQ[r] = (c < 128) ? eb1[l * 128 + c] : 0.0f;
    } else if (idx < 246528) {               // biasCPQ: [256]
        int c = idx - 246272;
        biasCPQ[c] = (c < 128) ? cb1[c] : 0.0f;
    }
}

// ---------------------------------------------------------------------------
// Counting sort of edges by destination row (ei[0][e]).
// ---------------------------------------------------------------------------
__global__ void k_hist(const int* __restrict__ ei, int* __restrict__ cnt) {
    int e = blockIdx.x * 256 + threadIdx.x;
    if (e < E_N) atomicAdd(&cnt[ei[e]], 1);
}

__global__ __launch_bounds__(1024) void k_scan(const int* __restrict__ cnt,
                                               int* __restrict__ off) {
    __shared__ int wsum[16];
    __shared__ int wscan[16];
    __shared__ int carry_s;
    int tid = threadIdx.x;
    int lane = tid & 63, wid = tid >> 6;
    if (tid == 0) carry_s = 0;
    __syncthreads();
    for (int base = 0; base < V_N; base += 1024) {
        int carry = carry_s;
        int i = base + tid;
        int v = (i < V_N) ? cnt[i] : 0;
        int val = v;
#pragma unroll
        for (int d = 1; d < 64; d <<= 1) {
            int t = __shfl_up(val, d, 64);
            if (lane >= d) val += t;
        }
        if (lane == 63) wsum[wid] = val;
        __syncthreads();
        if (tid == 0) {
            int s = 0;
#pragma unroll
            for (int k = 0; k < 16; k++) { s += wsum[k]; wscan[k] = s; }
        }
        __syncthreads();
        int wbase = wid ? wscan[wid - 1] : 0;
        if (i < V_N) off[i] = carry + wbase + val - v;
        __syncthreads();
        if (tid == 0) carry_s = carry + wscan[15];
        __syncthreads();
    }
}

__global__ void k_scatter(const int* __restrict__ ei, int* __restrict__ off,
                          int* __restrict__ srow, int* __restrict__ scol,
                          int* __restrict__ perm) {
    int e = blockIdx.x * 256 + threadIdx.x;
    if (e >= E_N) return;
    int r = ei[e], c = ei[E_N + e];
    int p = atomicAdd(&off[r], 1);
    srow[p] = r;
    scol[p] = c;
    perm[p] = e;
}

__global__ void k_edgeprep2(const int* __restrict__ perm, const int* __restrict__ srow,
                            const int* __restrict__ scol, const float* __restrict__ x,
                            const float* __restrict__ eattr,
                            float* __restrict__ cd, float* __restrict__ ea2) {
    int p = blockIdx.x * 256 + threadIdx.x;
    if (p >= E_N) return;
    int e = perm[p];
    int r = srow[p], c = scol[p];
    float dx = x[r * 3 + 0] - x[c * 3 + 0];
    float dy = x[r * 3 + 1] - x[c * 3 + 1];
    float dz = x[r * 3 + 2] - x[c * 3 + 2];
    float rad = dx * dx + dy * dy + dz * dz;
    float inv = 1.0f / (sqrtf(rad + 1e-8f) + 1.0f);
    cd[p * 3 + 0] = dx * inv;
    cd[p * 3 + 1] = dy * inv;
    cd[p * 3 + 2] = dz * inv;
    ea2[p * 2 + 0] = rad;
    ea2[p * 2 + 1] = eattr[e];
}

// ---------------------------------------------------------------------------
// Generic node-level GEMM. opq=1 writes the all-bf16 PQ layout (512B rows).
// ---------------------------------------------------------------------------
__global__ __launch_bounds__(256) void k_node_gemm(
    const float* __restrict__ A1, const float* __restrict__ A2,
    const bf16* __restrict__ BT, const float* __restrict__ bias,
    const float* __restrict__ resid, float* __restrict__ C,
    int M, int K, int Ntot, int act, int opq) {
    __shared__ __align__(16) bf16 Asl[64][136];
    __shared__ __align__(16) bf16 Bsl[128][136];
    int tid = threadIdx.x;
    int m0 = blockIdx.x * 64;
    int n0 = blockIdx.y * 128;
    int lane = tid & 63, w = tid >> 6;
    int q = lane >> 4, l15 = lane & 15;

    f32x4 acc[8];
#pragma unroll
    for (int i = 0; i < 8; i++) acc[i] = (f32x4){0.f, 0.f, 0.f, 0.f};

    for (int kc = 0; kc < K; kc += 128) {
        const float* Asrc = (kc == 0) ? A1 : A2;
#pragma unroll
        for (int p = 0; p < 8; p++) {
            int e4 = (p * 256 + tid) * 4;
            int r = e4 >> 7, k = e4 & 127;
            float4 v = {0.f, 0.f, 0.f, 0.f};
            int row = m0 + r;
            if (row < M) v = *(const float4*)&Asrc[(size_t)row * 128 + k];
            bf16x4 b4 = {(bf16)v.x, (bf16)v.y, (bf16)v.z, (bf16)v.w};
            *(bf16x4*)&Asl[r][k] = b4;
        }
#pragma unroll
        for (int p = 0; p < 8; p++) {
            int e8 = (p * 256 + tid) * 8;
            int n = e8 >> 7, k = e8 & 127;
            bf16x8 v = *(const bf16x8*)&BT[(size_t)(n0 + n) * K + kc + k];
            *(bf16x8*)&Bsl[n][k] = v;
        }
        __syncthreads();
        int ar = w * 16 + l15;
#pragma unroll
        for (int kt = 0; kt < 4; kt++) {
            bf16x8 a = *(const bf16x8*)&Asl[ar][kt * 32 + q * 8];
#pragma unroll
            for (int nt = 0; nt < 8; nt++) {
                bf16x8 b = *(const bf16x8*)&Bsl[nt * 16 + l15][kt * 32 + q * 8];
                acc[nt] = __builtin_amdgcn_mfma_f32_16x16x32_bf16(a, b, acc[nt], 0, 0, 0);
            }
        }
        __syncthreads();
    }
#pragma unroll
    for (int nt = 0; nt < 8; nt++) {
        int col = n0 + nt * 16 + l15;
        float bv = bias ? bias[col] : 0.0f;
#pragma unroll
        for (int reg = 0; reg < 4; reg++) {
            int row = m0 + w * 16 + q * 4 + reg;
            if (row < M) {
                float v = acc[nt][reg] + bv;
                if (act) v = silu_f(v);
                if (resid) v += resid[(size_t)row * 128 + (col & 127)];
                if (opq) {
                    *(bf16*)((char*)C + (size_t)row * PQ_STRIDE + col * 2) = (bf16)v;
                } else {
                    C[(size_t)row * Ntot + col] = v;
                }
            }
        }
    }
}

// ---------------------------------------------------------------------------
// Fused node MLP + next projection.
// ---------------------------------------------------------------------------
__global__ __launch_bounds__(256) void k_node_mlp(
    float* __restrict__ A2,             // agg (zeroed in place if zeroA2)
    const bf16* __restrict__ B1T,       // nw1T [128][256]
    const float* __restrict__ b1,
    const bf16* __restrict__ B2T,       // nw2T [128][128]
    const float* __restrict__ b2,
    float* __restrict__ H,              // outh, in/out
    int M, int zeroA2,
    const bf16* __restrict__ PT,        // next proj [256][128]
    const float* __restrict__ pbias,    // 256 (eb1 in P half, 0 in Q half)
    char* __restrict__ PQout) {
    __shared__ __align__(16) bf16 Asl[64][136];
    __shared__ __align__(16) bf16 Bsl[128][136];
    int tid = threadIdx.x;
    int m0 = blockIdx.x * 64;
    int lane = tid & 63, w = tid >> 6;
    int q = lane >> 4, l15 = lane & 15;
    int ar = w * 16 + l15;

    f32x4 acc[8];
#pragma unroll
    for (int i = 0; i < 8; i++) acc[i] = (f32x4){0.f, 0.f, 0.f, 0.f};

    for (int kc = 0; kc < 256; kc += 128) {
        const float* Asrc = (kc == 0) ? H : A2;
#pragma unroll
        for (int p = 0; p < 8; p++) {
            int e4 = (p * 256 + tid) * 4;
            int r = e4 >> 7, k = e4 & 127;
            float4 v = {0.f, 0.f, 0.f, 0.f};
            int row = m0 + r;
            if (row < M) v = *(const float4*)&Asrc[(size_t)row * 128 + k];
            bf16x4 b4 = {(bf16)v.x, (bf16)v.y, (bf16)v.z, (bf16)v.w};
            *(bf16x4*)&Asl[r][k] = b4;
            if (kc == 128 && zeroA2 && row < M) {
                *(float4*)&A2[(size_t)row * 128 + k] = (float4){0.f, 0.f, 0.f, 0.f};
            }
        }
#pragma unroll
        for (int p = 0; p < 8; p++) {
            int e8 = (p * 256 + tid) * 8;
            int n = e8 >> 7, k = e8 & 127;
            bf16x8 v = *(const bf16x8*)&B1T[(size_t)n * 256 + kc + k];
            *(bf16x8*)&Bsl[n][k] = v;
        }
        __syncthreads();
#pragma unroll
        for (int kt = 0; kt < 4; kt++) {
            bf16x8 a = *(const bf16x8*)&Asl[ar][kt * 32 + q * 8];
#pragma unroll
            for (int nt = 0; nt < 8; nt++) {
                bf16x8 b = *(const bf16x8*)&Bsl[nt * 16 + l15][kt * 32 + q * 8];
                acc[nt] = __builtin_amdgcn_mfma_f32_16x16x32_bf16(a, b, acc[nt], 0, 0, 0);
            }
        }
        __syncthreads();
    }
#pragma unroll
    for (int nt = 0; nt < 8; nt++) {
        float bv = b1[nt * 16 + l15];
#pragma unroll
        for (int reg = 0; reg < 4; reg++) {
            int r = w * 16 + q * 4 + reg;
            Asl[r][nt * 16 + l15] = (bf16)silu_f(acc[nt][reg] + bv);
        }
    }
#pragma unroll
    for (int p = 0; p < 8; p++) {
        int e8 = (p * 256 + tid) * 8;
        int n = e8 >> 7, k = e8 & 127;
        *(bf16x8*)&Bsl[n][k] = *(const bf16x8*)&B2T[(size_t)n * 128 + k];
    }
    __syncthreads();
    f32x4 acc2[8];
#pragma unroll
    for (int i = 0; i < 8; i++) acc2[i] = (f32x4){0.f, 0.f, 0.f, 0.f};
#pragma unroll
    for (int kt = 0; kt < 4; kt++) {
        bf16x8 a = *(const bf16x8*)&Asl[ar][kt * 32 + q * 8];
#pragma unroll
        for (int nt = 0; nt < 8; nt++) {
            bf16x8 b = *(const bf16x8*)&Bsl[nt * 16 + l15][kt * 32 + q * 8];
            acc2[nt] = __builtin_amdgcn_mfma_f32_16x16x32_bf16(a, b, acc2[nt], 0, 0, 0);
        }
    }
    // residual add -> Hnew (kept in acc2)
#pragma unroll
    for (int nt = 0; nt < 8; nt++) {
        int col = nt * 16 + l15;
        float bv = b2[col];
#pragma unroll
        for (int reg = 0; reg < 4; reg++) {
            int row = m0 + w * 16 + q * 4 + reg;
            if (row < M) {
                float hv = H[(size_t)row * 128 + col] + acc2[nt][reg] + bv;
                H[(size_t)row * 128 + col] = hv;
                acc2[nt][reg] = hv;
            }
        }
    }
    __syncthreads();   // all GEMM2 LDS reads done
#pragma unroll
    for (int nt = 0; nt < 8; nt++) {
#pragma unroll
        for (int reg = 0; reg < 4; reg++) {
            int r = w * 16 + q * 4 + reg;
            Asl[r][nt * 16 + l15] = (bf16)acc2[nt][reg];
        }
    }
    // fused projection: PQ = Hnew @ PT + pbias, two 128-col halves
    for (int half = 0; half < 2; half++) {
#pragma unroll
        for (int p = 0; p < 8; p++) {
            int e8 = (p * 256 + tid) * 8;
            int n = e8 >> 7, k = e8 & 127;
            *(bf16x8*)&Bsl[n][k] = *(const bf16x8*)&PT[(size_t)(half * 128 + n) * 128 + k];
        }
        __syncthreads();
        f32x4 accp[8];
#pragma unroll
        for (int i = 0; i < 8; i++) accp[i] = (f32x4){0.f, 0.f, 0.f, 0.f};
#pragma unroll
        for (int kt = 0; kt < 4; kt++) {
            bf16x8 a = *(const bf16x8*)&Asl[ar][kt * 32 + q * 8];
#pragma unroll
            for (int nt = 0; nt < 8; nt++) {
                bf16x8 b = *(const bf16x8*)&Bsl[nt * 16 + l15][kt * 32 + q * 8];
                accp[nt] = __builtin_amdgcn_mfma_f32_16x16x32_bf16(a, b, accp[nt], 0, 0, 0);
            }
        }
#pragma unroll
        for (int nt = 0; nt < 8; nt++) {
            int colg = half * 128 + nt * 16 + l15;
            float bv = pbias[colg];
#pragma unroll
            for (int reg = 0; reg < 4; reg++) {
                int row = m0 + w * 16 + q * 4 + reg;
                if (row < M) {
                    *(bf16*)(PQout + (size_t)row * PQ_STRIDE + colg * 2) =
                        (bf16)(accp[nt][reg] + bv);
                }
            }
        }
        __syncthreads();
    }
}

// ---------------------------------------------------------------------------
// Persistent fused GCL edge kernel: 512 threads, 128 sorted edges/tile.
// Fully wave-private tile body: stage-A, MFMA, epilogue, AND the reduce
// scratch all live in wave w's own 16 A-rows -> ONE barrier per tile (B1).
// Fsl slice layout: (col,edge) -> Asl[w*16 + col/8][(col&7)*16 + edge].
// ---------------------------------------------------------------------------
#define NTILES (E_N / 128)

__global__ __launch_bounds__(512, 4) void k_edge_gcl(
    const int* __restrict__ srow, const int* __restrict__ scol,
    const char* __restrict__ PQ,
    const float* __restrict__ ea2, const float* __restrict__ w1c,
    const bf16* __restrict__ ew2T,
    const float* __restrict__ eb2, const float* __restrict__ aw,
    const float* __restrict__ ab, float* __restrict__ agg) {
    __shared__ __align__(16) bf16 Asl[128][136];   // A-tile; wave-private Fsl slices
    __shared__ __align__(16) bf16 Bsl[128][136];   // persistent weight tile
    __shared__ int rows_s[2][128];
    __shared__ int cols_s[2][128];
    __shared__ float ra_s[2][128], aa_s[2][128];
    int tid = threadIdx.x;
    int lane = tid & 63, w = tid >> 6, q = lane >> 4, l15 = lane & 15;
    int j8 = l15 * 8;          // fixed 8-column group per lane
    int eg4 = lane >> 4;       // edge-in-pass within this wave (0..3)

    // stage B once
#pragma unroll
    for (int p = 0; p < 4; p++) {
        int e8 = (p * 512 + tid) * 8;
        int n = e8 >> 7, k = e8 & 127;
        *(bf16x8*)&Bsl[n][k] = *(const bf16x8*)&ew2T[n * 128 + k];
    }
    float4 w0a = *(const float4*)&w1c[j8];
    float4 w0b = *(const float4*)&w1c[j8 + 4];
    float4 w1a = *(const float4*)&w1c[128 + j8];
    float4 w1b = *(const float4*)&w1c[128 + j8 + 4];
    float b2v[8], awv[8];
#pragma unroll
    for (int nt = 0; nt < 8; nt++) {
        b2v[nt] = eb2[nt * 16 + l15];
        awv[nt] = aw[nt * 16 + l15];
    }
    float ab0 = ab[0];

    // prologue: stage meta(t0) into buffer 0
    int t0 = blockIdx.x;
    if (tid < 128) {
        int e = t0 * 128 + tid;
        rows_s[0][tid] = srow[e];
        cols_s[0][tid] = scol[e];
        float2 rr = *(const float2*)&ea2[(size_t)e * 2];
        ra_s[0][tid] = rr.x;
        aa_s[0][tid] = rr.y;
    }

    int b = 0;
    for (int t = t0; t < NTILES; t += gridDim.x, b ^= 1) {
        int tn = t + gridDim.x;
        __syncthreads();   // B1: prev reduce done; meta[b] visible
        if (tn < NTILES && tid < 128) {
            int e = tn * 128 + tid;
            rows_s[b ^ 1][tid] = srow[e];
            cols_s[b ^ 1][tid] = scol[e];
            float2 rr = *(const float2*)&ea2[(size_t)e * 2];
            ra_s[b ^ 1][tid] = rr.x;
            aa_s[b ^ 1][tid] = rr.y;
        }
        // stage A (wave-private): 4 passes x 4 edges of THIS wave's 16 edges
        bf16x8 pb[4];
        bf16x8 qb[4];
#pragma unroll
        for (int p = 0; p < 4; p++) {
            int el = w * 16 + p * 4 + eg4;
            int row = rows_s[b][el], col = cols_s[b][el];
            pb[p] = *(const bf16x8*)(PQ + (size_t)row * PQ_STRIDE + j8 * 2);
            qb[p] = *(const bf16x8*)(PQ + (size_t)col * PQ_STRIDE + 256 + j8 * 2);
        }
#pragma unroll
        for (int p = 0; p < 4; p++) {
            int el = w * 16 + p * 4 + eg4;
            float ra = ra_s[b][el], aa = aa_s[b][el];
            bf16x8 m8;
            float z;
            z = (float)pb[p][0] + (float)qb[p][0]; z = fmaf(aa, w1a.x, fmaf(ra, w0a.x, z)); m8[0] = (bf16)silu_f(z);
            z = (float)pb[p][1] + (float)qb[p][1]; z = fmaf(aa, w1a.y, fmaf(ra, w0a.y, z)); m8[1] = (bf16)silu_f(z);
            z = (float)pb[p][2] + (float)qb[p][2]; z = fmaf(aa, w1a.z, fmaf(ra, w0a.z, z)); m8[2] = (bf16)silu_f(z);
            z = (float)pb[p][3] + (float)qb[p][3]; z = fmaf(aa, w1a.w, fmaf(ra, w0a.w, z)); m8[3] = (bf16)silu_f(z);
            z = (float)pb[p][4] + (float)qb[p][4]; z = fmaf(aa, w1b.x, fmaf(ra, w0b.x, z)); m8[4] = (bf16)silu_f(z);
            z = (float)pb[p][5] + (float)qb[p][5]; z = fmaf(aa, w1b.y, fmaf(ra, w0b.y, z)); m8[5] = (bf16)silu_f(z);
            z = (float)pb[p][6] + (float)qb[p][6]; z = fmaf(aa, w1b.z, fmaf(ra, w0b.z, z)); m8[6] = (bf16)silu_f(z);
            z = (float)pb[p][7] + (float)qb[p][7]; z = fmaf(aa, w1b.w, fmaf(ra, w0b.w, z)); m8[7] = (bf16)silu_f(z);
            *(bf16x8*)&Asl[el][j8] = m8;
        }
        // no barrier: wave w only reads rows w*16..w*16+15 (written above)
        f32x4 acc[8];
#pragma unroll
        for (int i = 0; i < 8; i++) acc[i] = (f32x4){0.f, 0.f, 0.f, 0.f};
        int ar = w * 16 + l15;
#pragma unroll
        for (int kt = 0; kt < 4; kt++) {
            bf16x8 a = *(const bf16x8*)&Asl[ar][kt * 32 + q * 8];
#pragma unroll
            for (int nt = 0; nt < 8; nt++) {
                bf16x8 bb = *(const bf16x8*)&Bsl[nt * 16 + l15][kt * 32 + q * 8];
                acc[nt] = __builtin_amdgcn_mfma_f32_16x16x32_bf16(a, bb, acc[nt], 0, 0, 0);
            }
        }
        // epilogue in regs: silu + attention dot
        float partial[4] = {0.f, 0.f, 0.f, 0.f};
#pragma unroll
        for (int nt = 0; nt < 8; nt++) {
#pragma unroll
            for (int reg = 0; reg < 4; reg++) {
                float mv = silu_f(acc[nt][reg] + b2v[nt]);
                acc[nt][reg] = mv;
                partial[reg] += mv * awv[nt];
            }
        }
        float scale[4];
#pragma unroll
        for (int reg = 0; reg < 4; reg++) {
            float s = partial[reg];
            s += __shfl_xor(s, 1, 16);
            s += __shfl_xor(s, 2, 16);
            s += __shfl_xor(s, 4, 16);
            s += __shfl_xor(s, 8, 16);
            scale[reg] = sigmoid_f(s + ab0) * 0.01f;
        }
        // NO BARRIER: Fsl slice lives in wave w's own 16 rows.
        // (col,edge) -> Asl[w*16 + col/8][(col&7)*16 + edge]
        // lane (q,l15) writes col = nt*16+l15, edge = q*4+reg.
#pragma unroll
        for (int reg = 0; reg < 4; reg++) {
            int er = q * 4 + reg;   // edge index within wave (0..15)
            float sc = scale[reg];
#pragma unroll
            for (int nt = 0; nt < 8; nt++) {
                int colg = nt * 16 + l15;
                Asl[w * 16 + (colg >> 3)][(colg & 7) * 16 + er] =
                    (bf16)(acc[nt][reg] * sc);
            }
        }
        // wave-private reduce: lane handles cols c0=lane, c1=lane+64;
        // each col's 16 edge-values are contiguous: 2 x b128 reads.
        int c0 = lane, c1 = lane + 64;
        const bf16* r0 = &Asl[w * 16 + (c0 >> 3)][(c0 & 7) * 16];
        const bf16* r1 = &Asl[w * 16 + (c1 >> 3)][(c1 & 7) * 16];
        bf16x8 f0a = *(const bf16x8*)r0;
        bf16x8 f0b = *(const bf16x8*)(r0 + 8);
        bf16x8 f1a = *(const bf16x8*)r1;
        bf16x8 f1b = *(const bf16x8*)(r1 + 8);
        int eb = w * 16;
        float s0 = 0.f, s1 = 0.f;
#pragma unroll
        for (int el = 0; el < 16; ++el) {
            float v0 = (el < 8) ? (float)f0a[el & 7] : (float)f0b[el & 7];
            float v1 = (el < 8) ? (float)f1a[el & 7] : (float)f1b[el & 7];
            s0 += v0;
            s1 += v1;
            int r = rows_s[b][eb + el];
            int nxt = (el < 15) ? rows_s[b][eb + el + 1] : -1;
            if (r != nxt) {
                atomicAdd(&agg[(size_t)r * 128 + c0], s0);
                atomicAdd(&agg[(size_t)r * 128 + c1], s1);
                s0 = 0.f;
                s1 = 0.f;
            }
        }
    }
}

// ---------------------------------------------------------------------------
// Persistent fused coord-update edge kernel: wave-private stage-A + Ssl
// reduce -> 1 barrier/tile.
// ---------------------------------------------------------------------------
__global__ __launch_bounds__(512, 4) void k_edge_coord(
    const int* __restrict__ srow, const int* __restrict__ scol,
    const char* __restrict__ PQ,
    const float* __restrict__ ea2, const float* __restrict__ c1c,
    const bf16* __restrict__ cw2T,
    const float* __restrict__ cb2, const float* __restrict__ cw3,
    const float* __restrict__ cd, float* __restrict__ xagg) {
    __shared__ __align__(16) bf16 Asl[128][136];
    __shared__ __align__(16) bf16 Bsl[128][136];
    __shared__ int rows_s[2][128];
    __shared__ int cols_s[2][128];
    __shared__ float ra_s[2][128], aa_s[2][128];
    __shared__ float cds[2][384];
    __shared__ float Ssl[128];
    int tid = threadIdx.x;
    int lane = tid & 63, w = tid >> 6, q = lane >> 4, l15 = lane & 15;
    int j8 = l15 * 8;
    int eg4 = lane >> 4;

#pragma unroll
    for (int p = 0; p < 4; p++) {
        int e8 = (p * 512 + tid) * 8;
        int n = e8 >> 7, k = e8 & 127;
        *(bf16x8*)&Bsl[n][k] = *(const bf16x8*)&cw2T[n * 128 + k];
    }
    float4 w0a = *(const float4*)&c1c[j8];
    float4 w0b = *(const float4*)&c1c[j8 + 4];
    float4 w1a = *(const float4*)&c1c[128 + j8];
    float4 w1b = *(const float4*)&c1c[128 + j8 + 4];
    float b2v[8], w3v[8];
#pragma unroll
    for (int nt = 0; nt < 8; nt++) {
        b2v[nt] = cb2[nt * 16 + l15];
        w3v[nt] = cw3[nt * 16 + l15];
    }

    int t0 = blockIdx.x;
    if (tid < 128) {
        int e = t0 * 128 + tid;
        rows_s[0][tid] = srow[e];
        cols_s[0][tid] = scol[e];
        float2 rr = *(const float2*)&ea2[(size_t)e * 2];
        ra_s[0][tid] = rr.x;
        aa_s[0][tid] = rr.y;
    }
    if (tid < 384) cds[0][tid] = cd[(size_t)t0 * 384 + tid];

    int b = 0;
    for (int t = t0; t < NTILES; t += gridDim.x, b ^= 1) {
        int tn = t + gridDim.x;
        __syncthreads();   // B1
        if (tn < NTILES) {
            if (tid < 128) {
                int e = tn * 128 + tid;
                rows_s[b ^ 1][tid] = srow[e];
                cols_s[b ^ 1][tid] = scol[e];
                float2 rr = *(const float2*)&ea2[(size_t)e * 2];
                ra_s[b ^ 1][tid] = rr.x;
                aa_s[b ^ 1][tid] = rr.y;
            }
            if (tid < 384) cds[b ^ 1][tid] = cd[(size_t)tn * 384 + tid];
        }
        bf16x8 pb[4];
        bf16x8 qb[4];
#pragma unroll
        for (int p = 0; p < 4; p++) {
            int el = w * 16 + p * 4 + eg4;
            int row = rows_s[b][el], col = cols_s[b][el];
            pb[p] = *(const bf16x8*)(PQ + (size_t)row * PQ_STRIDE + j8 * 2);
            qb[p] = *(const bf16x8*)(PQ + (size_t)col * PQ_STRIDE + 256 + j8 * 2);
        }
#pragma unroll
        for (int p = 0; p < 4; p++) {
            int el = w * 16 + p * 4 + eg4;
            float ra = ra_s[b][el], aa = aa_s[b][el];
            bf16x8 m8;
            float z;
            z = (float)pb[p][0] + (float)qb[p][0]; z = fmaf(aa, w1a.x, fmaf(ra, w0a.x, z)); m8[0] = (bf16)silu_f(z);
            z = (float)pb[p][1] + (float)qb[p][1]; z = fmaf(aa, w1a.y, fmaf(ra, w0a.y, z)); m8[1] = (bf16)silu_f(z);
            z = (float)pb[p][2] + (float)qb[p][2]; z = fmaf(aa, w1a.z, fmaf(ra, w0a.z, z)); m8[2] = (bf16)silu_f(z);
            z = (float)pb[p][3] + (float)qb[p][3]; z = fmaf(aa, w1a.w, fmaf(ra, w0a.w, z)); m8[3] = (bf16)silu_f(z);
            z = (float)pb[p][4] + (float)qb[p][4]; z = fmaf(aa, w1b.x, fmaf(ra, w0b.x, z)); m8[4] = (bf16)silu_f(z);
            z = (float)pb[p][5] + (float)qb[p][5]; z = fmaf(aa, w1b.y, fmaf(ra, w0b.y, z)); m8[5] = (bf16)silu_f(z);
            z = (float)pb[p][6] + (float)qb[p][6]; z = fmaf(aa, w1b.z, fmaf(ra, w0b.z, z)); m8[6] = (bf16)silu_f(z);
            z = (float)pb[p][7] + (float)qb[p][7]; z = fmaf(aa, w1b.w, fmaf(ra, w0b.w, z)); m8[7] = (bf16)silu_f(z);
            *(bf16x8*)&Asl[el][j8] = m8;
        }
        // no barrier: wave-private rows
        f32x4 acc[8];
#pragma unroll
        for (int i = 0; i < 8; i++) acc[i] = (f32x4){0.f, 0.f, 0.f, 0.f};
        int ar = w * 16 + l15;
#pragma unroll
        for (int kt = 0; kt < 4; kt++) {
            bf16x8 a = *(const bf16x8*)&Asl[ar][kt * 32 + q * 8];
#pragma unroll
            for (int nt = 0; nt < 8; nt++) {
                bf16x8 bb = *(const bf16x8*)&Bsl[nt * 16 + l15][kt * 32 + q * 8];
                acc[nt] = __builtin_amdgcn_mfma_f32_16x16x32_bf16(a, bb, acc[nt], 0, 0, 0);
            }
        }
        float partial[4] = {0.f, 0.f, 0.f, 0.f};
#pragma unroll
        for (int nt = 0; nt < 8; nt++) {
#pragma unroll
            for (int reg = 0; reg < 4; reg++) {
                float tv = silu_f(acc[nt][reg] + b2v[nt]);
                partial[reg] += tv * w3v[nt];
            }
        }
#pragma unroll
        for (int reg = 0; reg < 4; reg++) {
            float s = partial[reg];
            s += __shfl_xor(s, 1, 16);
            s += __shfl_xor(s, 2, 16);
            s += __shfl_xor(s, 4, 16);
            s += __shfl_xor(s, 8, 16);
            if (l15 == 0) Ssl[w * 16 + q * 4 + reg] = s * 0.01f;
        }
        // wave-private segmented reduce (intra-wave Ssl, no barrier)
        if (lane < 3) {
            int d = lane;
            float sum = 0.f;
#pragma unroll
            for (int el = 0; el < 16; ++el) {
                int ge = w * 16 + el;
                sum += cds[b][ge * 3 + d] * Ssl[ge];
                int r = rows_s[b][ge];
                int nxt = (el < 15) ? rows_s[b][ge + 1] : -1;
                if (r != nxt) {
                    atomicAdd(&xagg[(size_t)r * 3 + d], sum);
                    sum = 0.f;
                }
            }
        }
    }
}

__global__ void k_finalx(const float* __restrict__ x, const float* __restrict__ xagg,
                         float* __restrict__ outx) {
    int i = blockIdx.x * 256 + threadIdx.x;
    if (i < V_N * 3) outx[i] = x[i] + xagg[i];
}

// ---------------------------------------------------------------------------
extern "C" void kernel_launch(void* const* d_in, const int* in_sizes, int n_in,
                              void* d_out, int out_size, void* d_ws, size_t ws_size,
                              hipStream_t stream) {
    const float* h = (const float*)d_in[0];
    const float* x = (const float*)d_in[1];
    const int* ei = (const int*)d_in[2];
    const float* eattr = (const float*)d_in[3];
    const float* ew1 = (const float*)d_in[4];
    const float* eb1 = (const float*)d_in[5];
    const float* ew2 = (const float*)d_in[6];
    const float* eb2 = (const float*)d_in[7];
    const float* aw = (const float*)d_in[8];
    const float* ab = (const float*)d_in[9];
    const float* nw1 = (const float*)d_in[10];
    const float* nb1 = (const float*)d_in[11];
    const float* nw2 = (const float*)d_in[12];
    const float* nb2 = (const float*)d_in[13];
    const float* cw1 = (const float*)d_in[14];
    const float* cb1 = (const float*)d_in[15];
    const float* cw2 = (const float*)d_in[16];
    const float* cb2 = (const float*)d_in[17];
    const float* cw3 = (const float*)d_in[18];

    char* ws = (char*)d_ws;
    size_t off_b = 0;
    auto alloc = [&](size_t b) {
        size_t o = off_b;
        off_b += (b + 255) & ~(size_t)255;
        return o;
    };
    float* cd = (float*)(ws + alloc((size_t)E_N * 3 * 4));
    float* ea2 = (float*)(ws + alloc((size_t)E_N * 2 * 4));
    char* PQ = (char*)(ws + alloc((size_t)V_N * PQ_STRIDE));
    float* agg = (float*)(ws + alloc((size_t)V_N * 128 * 4));
    float* xagg = (float*)(ws + alloc((size_t)V_N * 3 * 4));
    bf16* projT = (bf16*)(ws + alloc(2 * 256 * 128 * 2));
    bf16* ew2T = (bf16*)(ws + alloc(2 * 128 * 128 * 2));
    bf16* nw1T = (bf16*)(ws + alloc(2 * 128 * 256 * 2));
    bf16* nw2T = (bf16*)(ws + alloc(2 * 128 * 128 * 2));
    bf16* cprojT = (bf16*)(ws + alloc(256 * 128 * 2));
    bf16* cw2T = (bf16*)(ws + alloc(128 * 128 * 2));
    float* biasPQ = (float*)(ws + alloc(2 * 256 * 4));
    float* biasCPQ = (float*)(ws + alloc(256 * 4));
    int* cnt = (int*)(ws + alloc((size_t)V_N * 4));
    int* offv = (int*)(ws + alloc((size_t)V_N * 4));
    int* srow = (int*)(ws + alloc((size_t)E_N * 4));
    int* scol = (int*)(ws + alloc((size_t)E_N * 4));
    int* perm = (int*)(ws + alloc((size_t)E_N * 4));

    float* outh = (float*)d_out;
    float* outx = outh + (size_t)V_N * 128;

    hipMemcpyAsync(outh, h, (size_t)V_N * 128 * 4, hipMemcpyDeviceToDevice, stream);
    k_weights<<<964, 256, 0, stream>>>(ew1, ew2, nw1, nw2, cw1, cw2, eb1, cb1,
                                       projT, ew2T, nw1T, nw2T, cprojT, cw2T,
                                       biasPQ, biasCPQ);
    // counting sort of edges by row
    hipMemsetAsync(cnt, 0, (size_t)V_N * 4, stream);
    k_hist<<<(E_N + 255) / 256, 256, 0, stream>>>(ei, cnt);
    k_scan<<<1, 1024, 0, stream>>>(cnt, offv);
    k_scatter<<<(E_N + 255) / 256, 256, 0, stream>>>(ei, offv, srow, scol, perm);
    k_edgeprep2<<<(E_N + 255) / 256, 256, 0, stream>>>(perm, srow, scol, x, eattr, cd, ea2);
    hipMemsetAsync(xagg, 0, (size_t)V_N * 3 * 4, stream);
    hipMemsetAsync(agg, 0, (size_t)V_N * 128 * 4, stream);

    int mblocks = (V_N + 63) / 64;
    // layer 0: standalone projection (bias-folded)
    dim3 gproj(mblocks, 2);
    k_node_gemm<<<gproj, 256, 0, stream>>>(outh, nullptr, projT, biasPQ, nullptr,
                                           (float*)PQ, V_N, 128, 256, 0, 1);
    k_edge_gcl<<<512, 512, 0, stream>>>(
        srow, scol, PQ, ea2, ew1 + 256 * 128,
        ew2T, eb2, aw, ab, agg);
    // node MLP 0 (zeroes agg in place) + fused projection for layer 1
    k_node_mlp<<<mblocks, 256, 0, stream>>>(agg, nw1T, nb1, nw2T, nb2, outh, V_N, 1,
                                            projT + 256 * 128, biasPQ + 256, PQ);
    k_edge_gcl<<<512, 512, 0, stream>>>(
        srow, scol, PQ, ea2, ew1 + (size_t)1 * 258 * 128 + 256 * 128,
        ew2T + 128 * 128, eb2 + 128, aw + 128, ab + 1, agg);
    // node MLP 1 + fused coord projection
    k_node_mlp<<<mblocks, 256, 0, stream>>>(agg, nw1T + 128 * 256, nb1 + 128,
                                            nw2T + 128 * 128, nb2 + 128, outh, V_N, 0,
                                            cprojT, biasCPQ, PQ);
    k_edge_coord<<<512, 512, 0, stream>>>(srow, scol, PQ, ea2, cw1 + 256 * 128,
                                          cw2T, cb2, cw3, cd, xagg);
    k_finalx<<<(V_N * 3 + 255) / 256, 256, 0, stream>>>(x, xagg, outx);
}